// Round 12
// baseline (1313.869 us; speedup 1.0000x reference)
//
#include <hip/hip_runtime.h>
#include <hip/hip_cooperative_groups.h>
#include <math.h>

namespace cg = cooperative_groups;

#define G_    64
#define N_    512
#define NT_   32768
#define ET_   1048576
#define EPG_  16384
#define KP_   359
#define NP2_  22976
#define FIN_  128

struct Params {
    const int* row; const int* col; const float* ea;
    const float* x; const float* coords; const int* acls;
    const float* Bk; const float* posW; const float* posb;
    const float* W1s; const float* W1n; const float* b1;
    const float* gn1w; const float* gn1b; const float* gn1ms;
    const float* poolp;
    const float* W2s; const float* W2n; const float* b2;
    const float* gn2w; const float* gn2b; const float* gn2ms;
    const float* l1W; const float* l1b; const float* l2W; const float* l2b;
    float* y; float* hself; float* agg; float* aux;
    int2* rowcsr; int* colcsr; int* ccsr2;
    int* rowptr; int* colptr;
    int* histR8; int* histC8;
    float* deg; float* deg2; float* tanhv;
    int* perm; int* nmap; int* cls2;
    float* BkT; float* PT;
    float* statsP; float* readP;
    float* out;
};

__device__ __forceinline__
void gemm_unit(int unit, const float* __restrict__ in, int K,
               const float* __restrict__ Wa, const float* __restrict__ Wb,
               const float* __restrict__ bias,
               float* __restrict__ outA, float* __restrict__ outB,
               float* inT, int t) {
    int row0 = unit * 32;
    for (int idx = t; idx < 32 * K; idx += 256) inT[idx] = in[row0 * K + idx];
    __syncthreads();
    int c = t & 63, rb = t >> 6;
    const float* ip = inT + (rb * 8) * K;
    float aA[8] = {0,0,0,0,0,0,0,0};
    float aB[8] = {0,0,0,0,0,0,0,0};
    for (int k = 0; k < K; k += 4) {
        float wa0 = Wa[(k+0)*64 + c], wa1 = Wa[(k+1)*64 + c];
        float wa2 = Wa[(k+2)*64 + c], wa3 = Wa[(k+3)*64 + c];
        float wb0 = Wb[(k+0)*64 + c], wb1 = Wb[(k+1)*64 + c];
        float wb2 = Wb[(k+2)*64 + c], wb3 = Wb[(k+3)*64 + c];
        #pragma unroll
        for (int r = 0; r < 8; r++) {
            float4 xv = *(const float4*)&ip[r*K + k];
            aA[r] += xv.x*wa0; aB[r] += xv.x*wb0;
            aA[r] += xv.y*wa1; aB[r] += xv.y*wb1;
            aA[r] += xv.z*wa2; aB[r] += xv.z*wb2;
            aA[r] += xv.w*wa3; aB[r] += xv.w*wb3;
        }
    }
    float bv = bias[c];
    #pragma unroll
    for (int r = 0; r < 8; r++) {
        int node = row0 + rb*8 + r;
        outA[node*64 + c] = aA[r];
        outB[node*64 + c] = aB[r] + bv;
    }
    __syncthreads();
}

__global__ __launch_bounds__(256)
void k_mega(Params P) {
    cg::grid_group grid = cg::this_grid();
    __shared__ float smemF[4096];
    int* smemI = (int*)smemF;
    const int t = threadIdx.x;
    const int bx = blockIdx.x;
    const int NBg = gridDim.x;

    // P0: hist slices (512) + BkT (96) + PT (6)
    for (int b = bx; b < 614; b += NBg) {
        if (b < 512) {
            int g = b >> 3, s = b & 7;
            int* hr = smemI; int* hc = smemI + N_;
            for (int i = t; i < N_; i += 256) { hr[i] = 0; hc[i] = 0; }
            __syncthreads();
            int ebase = g * EPG_ + s * 2048;
            for (int i = t; i < 2048; i += 256) {
                atomicAdd(&hr[P.row[ebase + i] & (N_ - 1)], 1);
                atomicAdd(&hc[P.col[ebase + i] & (N_ - 1)], 1);
            }
            __syncthreads();
            int sbase = b * N_;
            for (int i = t; i < N_; i += 256) {
                P.histR8[sbase + i] = hr[i];
                P.histC8[sbase + i] = hc[i];
            }
            __syncthreads();
        } else if (b < 608) {
            int idx = (b - 512) * 256 + t;
            int c = idx >> 12, r = idx & 4095;
            int h = r >> 6, d = r & 63;
            P.BkT[c*4096 + d*64 + h] = P.Bk[c*4096 + h*64 + d];
        } else {
            int c = b - 608;
            int i = t >> 6, h = t & 63;
            const float* B = P.Bk + c*4096 + h*64;
            float acc = 0.f;
            for (int d = 0; d < 64; d++) {
                float vd = (i < 3) ? P.posW[i*64 + d] : P.posb[d];
                acc += B[d] * vd;
            }
            P.PT[c*256 + i*64 + h] = acc;
        }
    }
    grid.sync();

    // P1: per-graph scan
    for (int g = bx; g < G_; g += NBg) {
        int* hr = smemI; int* hc = smemI + N_;
        int nbase = g * N_;
        for (int i = t; i < N_; i += 256) {
            int sr = 0, sc = 0;
            #pragma unroll
            for (int s = 0; s < 8; s++) {
                sr += P.histR8[(g*8 + s)*N_ + i];
                sc += P.histC8[(g*8 + s)*N_ + i];
            }
            hr[i] = sr; hc[i] = sc;
            P.deg[nbase + i] = (float)sc;
            P.nmap[nbase + i] = -1;
        }
        __syncthreads();
        int wave = t >> 6, lane = t & 63;
        if (wave < 2) {
            int* h = wave ? hc : hr;
            int base8 = lane * 8;
            int loc[8];
            int tot = 0;
            #pragma unroll
            for (int i = 0; i < 8; i++) { int v = h[base8 + i]; loc[i] = tot; tot += v; }
            int pref = tot;
            for (int off = 1; off < 64; off <<= 1) {
                int u = __shfl_up(pref, off);
                if (lane >= off) pref += u;
            }
            pref -= tot;
            #pragma unroll
            for (int i = 0; i < 8; i++) h[base8 + i] = pref + loc[i];
        }
        __syncthreads();
        int ebase = g * EPG_;
        for (int i = t; i < N_; i += 256) {
            P.rowptr[nbase + i] = ebase + hr[i];
            P.colptr[nbase + i] = ebase + hc[i];
        }
        if (g == 0 && t == 0) { P.rowptr[NT_] = ET_; P.colptr[NT_] = ET_; }
        __syncthreads();
    }
    grid.sync();

    // P2: range-owned CSR scatter (512 units, 64-node ranges)
    for (int b = bx; b < 512; b += NBg) {
        int g = b >> 3, q = b & 7;
        int lo = q * 64;
        int* curR = smemI; int* curC = smemI + 64;
        int nbase = g * N_ + lo;
        if (t < 64) { curR[t] = P.rowptr[nbase + t]; curC[t] = P.colptr[nbase + t]; }
        __syncthreads();
        int ebase = g * EPG_;
        for (int i = t; i < EPG_; i += 256) {
            int rg = P.row[ebase + i];
            int cg2 = P.col[ebase + i];
            int rl = (rg & (N_ - 1)) - lo;
            if ((unsigned)rl < 64u) {
                int pr = atomicAdd(&curR[rl], 1);
                P.rowcsr[pr] = make_int2(cg2, __float_as_int(P.ea[ebase + i]));
            }
            int cl = (cg2 & (N_ - 1)) - lo;
            if ((unsigned)cl < 64u) {
                int pc = atomicAdd(&curC[cl], 1);
                P.colcsr[pc] = rg;
            }
        }
        __syncthreads();
    }
    grid.sync();

    // P3: stage-1 dual GEMM
    for (int u = bx; u < NT_/32; u += NBg)
        gemm_unit(u, P.x, FIN_, P.W1n, P.W1s, P.b1, P.y, P.hself, smemF, t);
    grid.sync();

    // P4: edge pulls — nsum + agg
    {
        float4* nsum = (float4*)P.aux;
        for (int u = bx; u < NT_/4; u += NBg) {
            int node = u * 4 + (t >> 6);
            int lane = t & 63;
            int rs = P.rowptr[node], re = P.rowptr[node + 1];
            float sx = 0.f, sy = 0.f, sz = 0.f, sw = 0.f;
            for (int k = rs + lane; k < re; k += 64) {
                int2 ent = P.rowcsr[k];
                int c = ent.x;
                float w = __int_as_float(ent.y);
                sx += w * P.coords[c*3+0];
                sy += w * P.coords[c*3+1];
                sz += w * P.coords[c*3+2];
                sw += w;
            }
            #pragma unroll
            for (int off = 32; off; off >>= 1) {
                sx += __shfl_xor(sx, off); sy += __shfl_xor(sy, off);
                sz += __shfl_xor(sz, off); sw += __shfl_xor(sw, off);
            }
            if (lane == 0) nsum[node] = make_float4(sx, sy, sz, sw);
            int cs = P.colptr[node], ce = P.colptr[node + 1];
            float acc = 0.f;
            #pragma unroll 8
            for (int k = cs; k < ce; k++) {
                int r = P.colcsr[k];
                acc += P.y[r*64 + lane];
            }
            P.agg[node*64 + lane] = acc;
        }
    }
    grid.sync();

    // P5: graph_norm stats stage 1
    for (int b = bx; b < G_*8; b += NBg) {
        float* r1 = smemF; float* r2 = smemF + 256;
        int g = b >> 3, chunk = b & 7;
        int c = t & 63, grp = t >> 6;
        int n0 = chunk * 64;
        float s1 = 0.f, s2 = 0.f;
        for (int n = n0 + grp; n < n0 + 64; n += 4) {
            int node = g * N_ + n;
            float v = P.hself[node*64 + c] + P.agg[node*64 + c] / fmaxf(P.deg[node], 1.f);
            s1 += v; s2 += v * v;
        }
        r1[t] = s1; r2[t] = s2;
        __syncthreads();
        if (grp == 0) {
            P.statsP[b*128 + c]      = r1[c] + r1[64+c] + r1[128+c] + r1[192+c];
            P.statsP[b*128 + 64 + c] = r2[c] + r2[64+c] + r2[128+c] + r2[192+c];
        }
        __syncthreads();
    }
    grid.sync();

    // P6: gn-finalize + apply + elu + delta + propagate
    {
        float4* nsum = (float4*)P.aux;
        for (int u = bx; u < NT_/4; u += NBg) {
            float* hT = smemF;
            int node = u * 4 + (t >> 6);
            int lane = t & 63;
            int g = node >> 9;
            float s1 = 0.f, s2 = 0.f;
            #pragma unroll
            for (int i = 0; i < 8; i++) {
                s1 += P.statsP[(g*8 + i)*128 + lane];
                s2 += P.statsP[(g*8 + i)*128 + 64 + lane];
            }
            float m = s1 / (float)N_, q = s2 / (float)N_, msv = P.gn1ms[lane];
            float var = q - msv * m * m * (2.f - msv);
            float mval = msv * m;
            float istd = rsqrtf(var + 1e-5f);
            float4 s4 = nsum[node];
            int c = P.acls[node];
            const float* Pt = P.PT + c * 256;
            float d = s4.x*Pt[lane] + s4.y*Pt[64+lane] + s4.z*Pt[128+lane] + s4.w*Pt[192+lane];
            float v = P.hself[node*64 + lane] + P.agg[node*64 + lane] / fmaxf(P.deg[node], 1.f);
            v = P.gn1w[lane] * (v - mval) * istd + P.gn1b[lane];
            v = v > 0.f ? v : expm1f(v);
            v += d;
            hT[t] = v;
            __syncthreads();
            float ssum = v;
            #pragma unroll
            for (int off = 32; off; off >>= 1) ssum += __shfl_xor(ssum, off);
            const float* B  = P.BkT + c * 4096;
            const float* hv = hT + (t & ~63);
            float acc = 0.f;
            #pragma unroll 8
            for (int j = 0; j < 64; j++) acc += B[j*64 + lane] * hv[j];
            P.hself[node*64 + lane] = acc + d * ssum;
            __syncthreads();
        }
    }
    grid.sync();

    // P7: top-k + ccsr2 remap + deg2
    for (int g = bx; g < G_; g += NBg) {
        float* key = smemF;
        int* idxS  = smemI + 512;
        int* lmap  = smemI + 1024;
        int* ideg  = smemI + 1536;
        float* pS  = smemF + 1936;
        if (t < 64) pS[t] = P.poolp[t];
        lmap[t] = -1; lmap[t + 256] = -1;
        for (int i = t; i < KP_; i += 256) ideg[i] = 0;
        __syncthreads();
        float nrm;
        {
            float s = 0.f;
            for (int i = 0; i < 64; i++) s += pS[i] * pS[i];
            nrm = sqrtf(s);
        }
        for (int n = t; n < N_; n += 256) {
            float acc = 0.f;
            const float* hv = P.hself + (size_t)(g*N_ + n) * 64;
            for (int cdx = 0; cdx < 64; cdx++) acc += hv[cdx] * pS[cdx];
            key[n]  = acc / nrm;
            idxS[n] = n;
        }
        __syncthreads();
        for (int k = 2; k <= N_; k <<= 1) {
            for (int j = k >> 1; j > 0; j >>= 1) {
                for (int i0 = t; i0 < N_; i0 += 256) {
                    int i = i0, ixj = i ^ j;
                    if (ixj > i) {
                        float ki = key[i], kj = key[ixj];
                        int   ii = idxS[i], ij = idxS[ixj];
                        bool before = (ki > kj) || (ki == kj && ii < ij);
                        bool dir = ((i & k) == 0);
                        if (dir ? !before : before) {
                            key[i] = kj; key[ixj] = ki;
                            idxS[i] = ij; idxS[ixj] = ii;
                        }
                    }
                }
                __syncthreads();
            }
        }
        for (int n = t; n < KP_; n += 256) {
            int orig  = idxS[n];
            int gnode = g * N_ + orig;
            int pj    = g * KP_ + n;
            P.perm[pj]  = gnode;
            P.tanhv[pj] = tanhf(key[n]);
            P.nmap[gnode] = pj;
            P.cls2[pj]  = P.acls[gnode];
            lmap[orig]  = pj;
        }
        __syncthreads();
        int ebase = g * EPG_;
        for (int k = t; k < EPG_; k += 256) {
            int mm = lmap[P.colcsr[ebase + k] & (N_ - 1)];
            P.ccsr2[ebase + k] = (mm >= 0) ? mm : NP2_;
        }
        for (int k = t; k < EPG_; k += 256) {
            int mr = lmap[P.row[ebase + k] & (N_ - 1)];
            int mc = lmap[P.col[ebase + k] & (N_ - 1)];
            if (mr >= 0 && mc >= 0) atomicAdd(&ideg[mc - g * KP_], 1);
        }
        __syncthreads();
        for (int i = t; i < KP_; i += 256) P.deg2[g * KP_ + i] = (float)ideg[i];
        __syncthreads();
    }
    grid.sync();

    // P8: s2prop
    if (bx == 0 && t < 64) P.y[(size_t)NP2_ * 64 + t] = 0.f;
    for (int u = bx; u < NP2_/4; u += NBg) {
        float* hT = smemF;
        int j = u * 4 + (t >> 6);
        int lane = t & 63;
        int orig = P.perm[j];
        int rs = P.rowptr[orig], re = P.rowptr[orig + 1];
        float sx = 0.f, sy = 0.f, sz = 0.f, sw = 0.f;
        for (int k = rs + lane; k < re; k += 64) {
            int c = P.rowcsr[k].x;
            if (P.nmap[c] >= 0) {
                sx += P.coords[c*3+0]; sy += P.coords[c*3+1]; sz += P.coords[c*3+2];
                sw += 1.f;
            }
        }
        #pragma unroll
        for (int off = 32; off; off >>= 1) {
            sx += __shfl_xor(sx, off); sy += __shfl_xor(sy, off);
            sz += __shfl_xor(sz, off); sw += __shfl_xor(sw, off);
        }
        int c = P.cls2[j];
        const float* Pt = P.PT + c * 256;
        float d = sx*Pt[lane] + sy*Pt[64+lane] + sz*Pt[128+lane] + sw*Pt[192+lane];
        float v = P.hself[orig*64 + lane] * P.tanhv[j] + d;
        hT[t] = v;
        __syncthreads();
        float ssum = v;
        #pragma unroll
        for (int off = 32; off; off >>= 1) ssum += __shfl_xor(ssum, off);
        const float* B  = P.BkT + c * 4096;
        const float* hv = hT + (t & ~63);
        float acc = 0.f;
        #pragma unroll 8
        for (int jj = 0; jj < 64; jj++) acc += B[jj*64 + lane] * hv[jj];
        P.agg[j*64 + lane] = acc + d * ssum;
        __syncthreads();
    }
    grid.sync();

    // P9: stage-2 dual GEMM
    for (int u = bx; u < NP2_/32; u += NBg)
        gemm_unit(u, P.agg, 64, P.W2n, P.W2s, P.b2, P.y, P.aux, smemF, t);
    grid.sync();

    // P10: gagg2 via ccsr2
    for (int u = bx; u < NP2_/4; u += NBg) {
        int j = u * 4 + (t >> 6);
        int lane = t & 63;
        int orig = P.perm[j];
        int start = P.colptr[orig], end = P.colptr[orig + 1];
        float acc = 0.f;
        #pragma unroll 8
        for (int k = start; k < end; k++) {
            int r = P.ccsr2[k];
            acc += P.y[r*64 + lane];
        }
        P.hself[j*64 + lane] = acc;
    }
    grid.sync();

    // P11: graph_norm stats stage 2
    for (int b = bx; b < G_*6; b += NBg) {
        float* r1 = smemF; float* r2 = smemF + 256;
        int g = b / 6, chunk = b % 6;
        int c = t & 63, grp = t >> 6;
        int n0 = chunk * 60, nend = min(n0 + 60, KP_);
        float s1 = 0.f, s2 = 0.f;
        for (int n = n0 + grp; n < nend; n += 4) {
            int node = g * KP_ + n;
            float v = P.aux[node*64 + c] + P.hself[node*64 + c] / fmaxf(P.deg2[node], 1.f);
            s1 += v; s2 += v * v;
        }
        r1[t] = s1; r2[t] = s2;
        __syncthreads();
        if (grp == 0) {
            P.statsP[b*128 + c]      = r1[c] + r1[64+c] + r1[128+c] + r1[192+c];
            P.statsP[b*128 + 64 + c] = r2[c] + r2[64+c] + r2[128+c] + r2[192+c];
        }
        __syncthreads();
    }
    grid.sync();

    // P12: gn-finalize + apply + elu + readout partials
    for (int b = bx; b < G_*6; b += NBg) {
        float* r1 = smemF; float* r2 = smemF + 256;
        int g = b / 6, chunk = b % 6;
        int c = t & 63, grp = t >> 6;
        float s1 = 0.f, s2 = 0.f;
        #pragma unroll
        for (int i = 0; i < 6; i++) {
            s1 += P.statsP[(g*6 + i)*128 + c];
            s2 += P.statsP[(g*6 + i)*128 + 64 + c];
        }
        float mean = s1 / (float)KP_, q = s2 / (float)KP_, msv = P.gn2ms[c];
        float var = q - msv * mean * mean * (2.f - msv);
        float mv = msv * mean;
        float is = rsqrtf(var + 1e-5f);
        float wv = P.gn2w[c], bv = P.gn2b[c];
        int n0 = chunk * 60, nend = min(n0 + 60, KP_);
        float s = 0.f, m = -1e30f;
        for (int n = n0 + grp; n < nend; n += 4) {
            int node = g * KP_ + n;
            float v = P.aux[node*64 + c] + P.hself[node*64 + c] / fmaxf(P.deg2[node], 1.f);
            v = wv * (v - mv) * is + bv;
            v = v > 0.f ? v : expm1f(v);
            s += v; m = fmaxf(m, v);
        }
        r1[t] = s; r2[t] = m;
        __syncthreads();
        if (grp == 0) {
            P.readP[b*128 + c]      = r1[c] + r1[64+c] + r1[128+c] + r1[192+c];
            P.readP[b*128 + 64 + c] = fmaxf(fmaxf(r2[c], r2[64+c]), fmaxf(r2[128+c], r2[192+c]));
        }
        __syncthreads();
    }
    grid.sync();

    // P13: readout finalize
    for (int g = bx; g < G_; g += NBg) {
        float* gv = smemF;
        float* rS = smemF + 192;
        if (t < 64) {
            float s = 0.f, m = -1e30f;
            for (int i = 0; i < 6; i++) {
                s += P.readP[(g*6 + i)*128 + t];
                m = fmaxf(m, P.readP[(g*6 + i)*128 + 64 + t]);
            }
            gv[t] = s / (float)KP_;
            gv[64 + t] = m;
            gv[128 + t] = s;
        }
        __syncthreads();
        if (t < 64) {
            float acc = P.l1b[t];
            for (int k = 0; k < 192; k++) acc += gv[k] * P.l1W[k*64 + t];
            rS[t] = fmaxf(acc, 0.f);
        }
        __syncthreads();
        if (t == 0) {
            float l0 = P.l2b[0], l1v = P.l2b[1];
            for (int hh = 0; hh < 64; hh++) {
                l0  += rS[hh] * P.l2W[hh*2+0];
                l1v += rS[hh] * P.l2W[hh*2+1];
            }
            float mx  = fmaxf(l0, l1v);
            float lse = mx + logf(expf(l0 - mx) + expf(l1v - mx));
            P.out[g*2 + 0] = l0  - lse;
            P.out[g*2 + 1] = l1v - lse;
        }
        __syncthreads();
    }
}

// ============================ fallback kernels (round-10 proven) ====================

__global__ __launch_bounds__(256)
void k_histprep(const int* __restrict__ row, const int* __restrict__ col,
                int* __restrict__ histR8, int* __restrict__ histC8,
                const float* __restrict__ Bk, const float* __restrict__ posW,
                const float* __restrict__ posb,
                float* __restrict__ BkT, float* __restrict__ PT) {
    int b = blockIdx.x, t = threadIdx.x;
    if (b < 512) {
        __shared__ int hr[N_], hc[N_];
        int g = b >> 3, s = b & 7;
        for (int i = t; i < N_; i += 256) { hr[i] = 0; hc[i] = 0; }
        __syncthreads();
        int ebase = g * EPG_ + s * 2048;
        for (int i = t; i < 2048; i += 256) {
            atomicAdd(&hr[row[ebase + i] & (N_ - 1)], 1);
            atomicAdd(&hc[col[ebase + i] & (N_ - 1)], 1);
        }
        __syncthreads();
        int sbase = b * N_;
        for (int i = t; i < N_; i += 256) {
            histR8[sbase + i] = hr[i];
            histC8[sbase + i] = hc[i];
        }
    } else if (b < 608) {
        int idx = (b - 512) * 256 + t;
        int c = idx >> 12, r = idx & 4095;
        int h = r >> 6, d = r & 63;
        BkT[c*4096 + d*64 + h] = Bk[c*4096 + h*64 + d];
    } else {
        int c = b - 608;
        int i = t >> 6, h = t & 63;
        const float* B = Bk + c*4096 + h*64;
        float acc = 0.f;
        for (int d = 0; d < 64; d++) {
            float vd = (i < 3) ? posW[i*64 + d] : posb[d];
            acc += B[d] * vd;
        }
        PT[c*256 + i*64 + h] = acc;
    }
}

__global__ __launch_bounds__(256)
void k_scan(const int* __restrict__ histR8, const int* __restrict__ histC8,
            int* __restrict__ rowptr, int* __restrict__ colptr,
            float* __restrict__ deg, int* __restrict__ nmap) {
    __shared__ int hr[N_], hc[N_];
    int g = blockIdx.x, t = threadIdx.x;
    int nbase = g * N_;
    for (int i = t; i < N_; i += 256) {
        int sr = 0, sc = 0;
        #pragma unroll
        for (int s = 0; s < 8; s++) {
            sr += histR8[(g*8 + s)*N_ + i];
            sc += histC8[(g*8 + s)*N_ + i];
        }
        hr[i] = sr; hc[i] = sc;
        deg[nbase + i] = (float)sc;
        nmap[nbase + i] = -1;
    }
    __syncthreads();
    int wave = t >> 6, lane = t & 63;
    if (wave < 2) {
        int* h = wave ? hc : hr;
        int base8 = lane * 8;
        int loc[8];
        int tot = 0;
        #pragma unroll
        for (int i = 0; i < 8; i++) { int v = h[base8 + i]; loc[i] = tot; tot += v; }
        int pref = tot;
        for (int off = 1; off < 64; off <<= 1) {
            int u = __shfl_up(pref, off);
            if (lane >= off) pref += u;
        }
        pref -= tot;
        #pragma unroll
        for (int i = 0; i < 8; i++) h[base8 + i] = pref + loc[i];
    }
    __syncthreads();
    int ebase = g * EPG_;
    for (int i = t; i < N_; i += 256) {
        rowptr[nbase + i] = ebase + hr[i];
        colptr[nbase + i] = ebase + hc[i];
    }
    if (g == 0 && t == 0) { rowptr[NT_] = ET_; colptr[NT_] = ET_; }
}

__global__ __launch_bounds__(1024)
void k_scat(const int* __restrict__ row, const int* __restrict__ col,
            const float* __restrict__ ea,
            const int* __restrict__ rowptr, const int* __restrict__ colptr,
            int2* __restrict__ rowcsr, int* __restrict__ colcsr) {
    __shared__ int curR[128], curC[128];
    int g = blockIdx.x >> 2, q = blockIdx.x & 3;
    int t = threadIdx.x;
    int lo = q * 128;
    int nbase = g * N_ + lo;
    if (t < 128) { curR[t] = rowptr[nbase + t]; curC[t] = colptr[nbase + t]; }
    __syncthreads();
    int ebase = g * EPG_;
    for (int i = t; i < EPG_; i += 1024) {
        int rg = row[ebase + i];
        int cg = col[ebase + i];
        int rl = (rg & (N_ - 1)) - lo;
        if ((unsigned)rl < 128u) {
            int pr = atomicAdd(&curR[rl], 1);
            rowcsr[pr] = make_int2(cg, __float_as_int(ea[ebase + i]));
        }
        int cl = (cg & (N_ - 1)) - lo;
        if ((unsigned)cl < 128u) {
            int pc = atomicAdd(&curC[cl], 1);
            colcsr[pc] = rg;
        }
    }
}

__global__ __launch_bounds__(256)
void k_gemm_dual(const float* __restrict__ in, int K,
                 const float* __restrict__ Wa, const float* __restrict__ Wb,
                 const float* __restrict__ bias,
                 float* __restrict__ outA, float* __restrict__ outB) {
    __shared__ float inT[32 * FIN_];
    gemm_unit(blockIdx.x, in, K, Wa, Wb, bias, outA, outB, inT, threadIdx.x);
}

__global__ __launch_bounds__(256)
void k_edge1f(const int* __restrict__ rowptr, const int2* __restrict__ rcsr,
              const int* __restrict__ colptr, const int* __restrict__ ccsr,
              const float* __restrict__ coords, const float* __restrict__ y,
              float4* __restrict__ nsum, float* __restrict__ agg) {
    int node = blockIdx.x * 4 + (threadIdx.x >> 6);
    int lane = threadIdx.x & 63;
    int rs = rowptr[node], re = rowptr[node + 1];
    float sx = 0.f, sy = 0.f, sz = 0.f, sw = 0.f;
    for (int k = rs + lane; k < re; k += 64) {
        int2 ent = rcsr[k];
        int c = ent.x;
        float w = __int_as_float(ent.y);
        sx += w * coords[c*3+0];
        sy += w * coords[c*3+1];
        sz += w * coords[c*3+2];
        sw += w;
    }
    #pragma unroll
    for (int off = 32; off; off >>= 1) {
        sx += __shfl_xor(sx, off); sy += __shfl_xor(sy, off);
        sz += __shfl_xor(sz, off); sw += __shfl_xor(sw, off);
    }
    if (lane == 0) nsum[node] = make_float4(sx, sy, sz, sw);
    int cs = colptr[node], ce = colptr[node + 1];
    float acc = 0.f;
    #pragma unroll 8
    for (int k = cs; k < ce; k++) {
        int r = ccsr[k];
        acc += y[r*64 + lane];
    }
    agg[node*64 + lane] = acc;
}

__global__ __launch_bounds__(256)
void k_gnstat(const float* __restrict__ hs, const float* __restrict__ agg,
              const float* __restrict__ deg, float* __restrict__ partial,
              int NPG, int CH, int npc) {
    __shared__ float r1[256], r2[256];
    int b = blockIdx.x;
    int g = b / CH, chunk = b % CH;
    int t = threadIdx.x, c = t & 63, grp = t >> 6;
    int n0 = chunk * npc;
    int nend = min(n0 + npc, NPG);
    float s1 = 0.f, s2 = 0.f;
    for (int n = n0 + grp; n < nend; n += 4) {
        int node = g * NPG + n;
        float v = hs[node*64 + c] + agg[node*64 + c] / fmaxf(deg[node], 1.f);
        s1 += v; s2 += v * v;
    }
    r1[t] = s1; r2[t] = s2;
    __syncthreads();
    if (grp == 0) {
        partial[b*128 + c]      = r1[c] + r1[64+c] + r1[128+c] + r1[192+c];
        partial[b*128 + 64 + c] = r2[c] + r2[64+c] + r2[128+c] + r2[192+c];
    }
}

__global__ __launch_bounds__(256)
void k_gnprop(const float* __restrict__ hself, const float* __restrict__ agg,
              const float* __restrict__ deg, const float* __restrict__ partial,
              const float* __restrict__ ms,
              const float* __restrict__ w, const float* __restrict__ b,
              const float4* __restrict__ nsum, const int* __restrict__ cls,
              const float* __restrict__ PT, const float* __restrict__ BkT,
              float* __restrict__ out) {
    __shared__ float hT[256];
    int t = threadIdx.x;
    int node = blockIdx.x * 4 + (t >> 6);
    int lane = t & 63;
    int g = (blockIdx.x * 4) >> 9;
    float s1 = 0.f, s2 = 0.f;
    #pragma unroll
    for (int i = 0; i < 8; i++) {
        s1 += partial[(g*8 + i)*128 + lane];
        s2 += partial[(g*8 + i)*128 + 64 + lane];
    }
    float m  = s1 / (float)N_, q = s2 / (float)N_, msv = ms[lane];
    float var = q - msv * m * m * (2.f - msv);
    float mval = msv * m;
    float istd = rsqrtf(var + 1e-5f);
    float4 s4 = nsum[node];
    int c = cls[node];
    const float* P = PT + c * 256;
    float d = s4.x*P[lane] + s4.y*P[64+lane] + s4.z*P[128+lane] + s4.w*P[192+lane];
    float v = hself[node*64 + lane] + agg[node*64 + lane] / fmaxf(deg[node], 1.f);
    v = w[lane] * (v - mval) * istd + b[lane];
    v = v > 0.f ? v : expm1f(v);
    v += d;
    hT[t] = v;
    __syncthreads();
    float ssum = v;
    #pragma unroll
    for (int off = 32; off; off >>= 1) ssum += __shfl_xor(ssum, off);
    const float* B  = BkT + c * 4096;
    const float* hv = hT + (t & ~63);
    float acc = 0.f;
    #pragma unroll 8
    for (int j = 0; j < 64; j++) acc += B[j*64 + lane] * hv[j];
    out[node*64 + lane] = acc + d * ssum;
}

__global__ __launch_bounds__(512)
void k_topk(const float* __restrict__ hp, const float* __restrict__ p,
            const int* __restrict__ cls, const int* __restrict__ ccsr,
            const int* __restrict__ row, const int* __restrict__ col,
            int* __restrict__ perm, float* __restrict__ tanhv,
            int* __restrict__ node_map, int* __restrict__ class2,
            int* __restrict__ ccsr2, float* __restrict__ deg2) {
    __shared__ float key[N_];
    __shared__ int   idxS[N_];
    __shared__ int   lmap[N_];
    __shared__ int   ideg[KP_];
    __shared__ float pS[64];
    __shared__ float nrm;
    int g = blockIdx.x, t = threadIdx.x;
    lmap[t] = -1;
    if (t < 64) pS[t] = p[t];
    for (int i = t; i < KP_; i += 512) ideg[i] = 0;
    __syncthreads();
    if (t == 0) {
        float s = 0.f;
        for (int i = 0; i < 64; i++) s += pS[i] * pS[i];
        nrm = sqrtf(s);
    }
    __syncthreads();
    {
        float acc = 0.f;
        const float* hv = hp + (size_t)(g*N_ + t) * 64;
        for (int cdx = 0; cdx < 64; cdx++) acc += hv[cdx] * pS[cdx];
        key[t]  = acc / nrm;
        idxS[t] = t;
    }
    __syncthreads();
    for (int k = 2; k <= N_; k <<= 1) {
        for (int j = k >> 1; j > 0; j >>= 1) {
            int i = t, ixj = i ^ j;
            if (ixj > i) {
                float ki = key[i], kj = key[ixj];
                int   ii = idxS[i], ij = idxS[ixj];
                bool before = (ki > kj) || (ki == kj && ii < ij);
                bool dir = ((i & k) == 0);
                if (dir ? !before : before) {
                    key[i] = kj; key[ixj] = ki;
                    idxS[i] = ij; idxS[ixj] = ii;
                }
            }
            __syncthreads();
        }
    }
    if (t < KP_) {
        int orig  = idxS[t];
        int gnode = g * N_ + orig;
        int pj    = g * KP_ + t;
        perm[pj]     = gnode;
        tanhv[pj]    = tanhf(key[t]);
        node_map[gnode] = pj;
        class2[pj]   = cls[gnode];
        lmap[orig]   = pj;
    }
    __syncthreads();
    int ebase = g * EPG_;
    for (int k = t; k < EPG_; k += 512) {
        int mm = lmap[ccsr[ebase + k] & (N_ - 1)];
        ccsr2[ebase + k] = (mm >= 0) ? mm : NP2_;
    }
    for (int k = t; k < EPG_; k += 512) {
        int mr = lmap[row[ebase + k] & (N_ - 1)];
        int mc = lmap[col[ebase + k] & (N_ - 1)];
        if (mr >= 0 && mc >= 0) atomicAdd(&ideg[mc - g * KP_], 1);
    }
    __syncthreads();
    for (int i = t; i < KP_; i += 512) deg2[g * KP_ + i] = (float)ideg[i];
}

__global__ __launch_bounds__(256)
void k_s2prop(const int* __restrict__ rowptr, const int2* __restrict__ rcsr,
              const int* __restrict__ perm, const int* __restrict__ nmap,
              const float* __restrict__ coords,
              const float* __restrict__ hp, const float* __restrict__ tanhv,
              const int* __restrict__ cls2,
              const float* __restrict__ PT, const float* __restrict__ BkT,
              float* __restrict__ out, float* __restrict__ y2zero) {
    __shared__ float hT[256];
    int t = threadIdx.x;
    int j = blockIdx.x * 4 + (t >> 6);
    int lane = t & 63;
    if (blockIdx.x == 0 && t < 64) y2zero[t] = 0.f;
    int orig = perm[j];
    int rs = rowptr[orig], re = rowptr[orig + 1];
    float sx = 0.f, sy = 0.f, sz = 0.f, sw = 0.f;
    for (int k = rs + lane; k < re; k += 64) {
        int c = rcsr[k].x;
        if (nmap[c] >= 0) {
            sx += coords[c*3+0]; sy += coords[c*3+1]; sz += coords[c*3+2];
            sw += 1.f;
        }
    }
    #pragma unroll
    for (int off = 32; off; off >>= 1) {
        sx += __shfl_xor(sx, off); sy += __shfl_xor(sy, off);
        sz += __shfl_xor(sz, off); sw += __shfl_xor(sw, off);
    }
    int c = cls2[j];
    const float* P = PT + c * 256;
    float d = sx*P[lane] + sy*P[64+lane] + sz*P[128+lane] + sw*P[192+lane];
    float v = hp[orig*64 + lane] * tanhv[j] + d;
    hT[t] = v;
    __syncthreads();
    float ssum = v;
    #pragma unroll
    for (int off = 32; off; off >>= 1) ssum += __shfl_xor(ssum, off);
    const float* B  = BkT + c * 4096;
    const float* hv = hT + (t & ~63);
    float acc = 0.f;
    #pragma unroll 8
    for (int jj = 0; jj < 64; jj++) acc += B[jj*64 + lane] * hv[jj];
    out[j*64 + lane] = acc + d * ssum;
}

__global__ __launch_bounds__(256)
void k_gagg2(const int* __restrict__ colptr, const int* __restrict__ ccsr2,
             const int* __restrict__ perm, const float* __restrict__ y2,
             float* __restrict__ agg2) {
    int j = blockIdx.x * 4 + (threadIdx.x >> 6);
    int lane = threadIdx.x & 63;
    int orig = perm[j];
    int start = colptr[orig], end = colptr[orig + 1];
    float acc = 0.f;
    #pragma unroll 8
    for (int k = start; k < end; k++) {
        int r = ccsr2[k];
        acc += y2[r*64 + lane];
    }
    agg2[j*64 + lane] = acc;
}

__global__ __launch_bounds__(256)
void k_gnrd(const float* __restrict__ hs, const float* __restrict__ agg,
            const float* __restrict__ deg2, const float* __restrict__ statsP,
            const float* __restrict__ ms,
            const float* __restrict__ w, const float* __restrict__ b,
            float* __restrict__ readP) {
    __shared__ float r1[256], r2[256];
    int blk = blockIdx.x;
    int g = blk / 6, chunk = blk % 6;
    int t = threadIdx.x, c = t & 63, grp = t >> 6;
    float s1 = 0.f, s2 = 0.f;
    #pragma unroll
    for (int i = 0; i < 6; i++) {
        s1 += statsP[(g*6 + i)*128 + c];
        s2 += statsP[(g*6 + i)*128 + 64 + c];
    }
    float mean = s1 / (float)KP_, q = s2 / (float)KP_, msv = ms[c];
    float var = q - msv * mean * mean * (2.f - msv);
    float mv = msv * mean;
    float is = rsqrtf(var + 1e-5f);
    float wv = w[c], bv = b[c];
    int n0 = chunk * 60, nend = min(n0 + 60, KP_);
    float s = 0.f, m = -1e30f;
    for (int n = n0 + grp; n < nend; n += 4) {
        int node = g * KP_ + n;
        float v = hs[node*64 + c] + agg[node*64 + c] / fmaxf(deg2[node], 1.f);
        v = wv * (v - mv) * is + bv;
        v = v > 0.f ? v : expm1f(v);
        s += v; m = fmaxf(m, v);
    }
    r1[t] = s; r2[t] = m;
    __syncthreads();
    if (grp == 0) {
        readP[blk*128 + c]      = r1[c] + r1[64+c] + r1[128+c] + r1[192+c];
        readP[blk*128 + 64 + c] = fmaxf(fmaxf(r2[c], r2[64+c]), fmaxf(r2[128+c], r2[192+c]));
    }
}

__global__ void k_rfin(const float* __restrict__ part, int CH,
                       const float* __restrict__ l1W, const float* __restrict__ l1b,
                       const float* __restrict__ l2W, const float* __restrict__ l2b,
                       float* __restrict__ out) {
    __shared__ float gv[192], rS[64];
    int g = blockIdx.x, t = threadIdx.x;
    float s = 0.f, m = -1e30f;
    for (int i = 0; i < CH; i++) {
        s += part[(g*CH + i)*128 + t];
        m = fmaxf(m, part[(g*CH + i)*128 + 64 + t]);
    }
    gv[t] = s / (float)KP_;
    gv[64 + t] = m;
    gv[128 + t] = s;
    __syncthreads();
    float acc = l1b[t];
    for (int k = 0; k < 192; k++) acc += gv[k] * l1W[k*64 + t];
    rS[t] = fmaxf(acc, 0.f);
    __syncthreads();
    if (t == 0) {
        float l0 = l2b[0], l1v = l2b[1];
        for (int hh = 0; hh < 64; hh++) { l0 += rS[hh]*l2W[hh*2+0]; l1v += rS[hh]*l2W[hh*2+1]; }
        float mx  = fmaxf(l0, l1v);
        float lse = mx + logf(expf(l0 - mx) + expf(l1v - mx));
        out[g*2 + 0] = l0  - lse;
        out[g*2 + 1] = l1v - lse;
    }
}

extern "C" void kernel_launch(void* const* d_in, const int* in_sizes, int n_in,
                              void* d_out, int out_size, void* d_ws, size_t ws_size,
                              hipStream_t stream) {
    float* W = (float*)d_ws;
    const size_t NTH = (size_t)NT_ * 64;
    float* b0    = W;
    float* b1buf = W + 1*NTH;
    float* b2buf = W + 2*NTH;
    float* b3buf = W + 3*NTH;
    float* p = W + 4*NTH;
    int2*  rowcsr = (int2*)p;        p += 2*(size_t)ET_;
    int*   colcsr = (int*)p;         p += ET_;
    int*   ccsr2  = (int*)p;         p += ET_;
    int*   rowptr = (int*)p;         p += NT_ + 8;
    int*   colptr = (int*)p;         p += NT_ + 8;
    int*   histR8 = (int*)p;         p += NT_ * 8;
    int*   histC8 = (int*)p;         p += NT_ * 8;
    float* deg    = p;               p += NT_;
    float* deg2   = p;               p += NP2_;
    float* tanhv  = p;               p += NP2_;
    int*   perm   = (int*)p;         p += NP2_;
    int*   nmap   = (int*)p;         p += NT_;
    int*   cls2   = (int*)p;         p += NP2_;
    float* BkT    = p;               p += 6 * 4096;
    float* PT     = p;               p += 6 * 256;
    float* statsP = p;               p += (size_t)G_ * 8 * 128;
    float* readP  = p;               p += (size_t)G_ * 6 * 128;

    Params P;
    P.row    = (const int*)d_in[1];
    P.col    = (const int*)d_in[1] + ET_;
    P.ea     = (const float*)d_in[2];
    P.x      = (const float*)d_in[0];
    P.coords = (const float*)d_in[3];
    P.acls   = (const int*)d_in[4];
    P.Bk     = (const float*)d_in[5];
    P.posW   = (const float*)d_in[6];
    P.posb   = (const float*)d_in[7];
    P.W1s    = (const float*)d_in[8];
    P.W1n    = (const float*)d_in[9];
    P.b1     = (const float*)d_in[10];
    P.gn1w   = (const float*)d_in[11];
    P.gn1b   = (const float*)d_in[12];
    P.gn1ms  = (const float*)d_in[13];
    P.poolp  = (const float*)d_in[14];
    P.W2s    = (const float*)d_in[15];
    P.W2n    = (const float*)d_in[16];
    P.b2     = (const float*)d_in[17];
    P.gn2w   = (const float*)d_in[18];
    P.gn2b   = (const float*)d_in[19];
    P.gn2ms  = (const float*)d_in[20];
    P.l1W    = (const float*)d_in[21];
    P.l1b    = (const float*)d_in[22];
    P.l2W    = (const float*)d_in[23];
    P.l2b    = (const float*)d_in[24];
    P.y = b0; P.hself = b1buf; P.agg = b2buf; P.aux = b3buf;
    P.rowcsr = rowcsr; P.colcsr = colcsr; P.ccsr2 = ccsr2;
    P.rowptr = rowptr; P.colptr = colptr;
    P.histR8 = histR8; P.histC8 = histC8;
    P.deg = deg; P.deg2 = deg2; P.tanhv = tanhv;
    P.perm = perm; P.nmap = nmap; P.cls2 = cls2;
    P.BkT = BkT; P.PT = PT; P.statsP = statsP; P.readP = readP;
    P.out = (float*)d_out;

    // Size the cooperative grid from measured occupancy (host-only queries;
    // free at graph-replay time since kernel_launch isn't re-run).
    int blocksPerCU = 0;
    hipError_t qerr = hipOccupancyMaxActiveBlocksPerMultiprocessor(
        &blocksPerCU, (const void*)k_mega, 256, 0);
    int dev = 0, ncu = 0;
    hipGetDevice(&dev);
    hipDeviceGetAttribute(&ncu, hipDeviceAttributeMultiprocessorCount, dev);
    long grid = (long)blocksPerCU * (long)ncu;
    if (grid > 1024) grid = 1024;

    hipError_t lerr = hipErrorUnknown;
    if (qerr == hipSuccess && grid >= 64) {
        void* args[] = { &P };
        lerr = hipLaunchCooperativeKernel((const void*)k_mega, dim3((int)grid),
                                          dim3(256), args, 0, stream);
    }
    if (lerr != hipSuccess) {
        // -------- fallback: proven round-10 multi-kernel path --------
        const int* row  = P.row;
        const int* colp = P.col;
        float4* nsum = (float4*)b3buf;
        k_histprep <<<614,     256,  0, stream>>>(row, colp, histR8, histC8,
                                                  P.Bk, P.posW, P.posb, BkT, PT);
        k_scan     <<<G_,      256,  0, stream>>>(histR8, histC8, rowptr, colptr,
                                                  deg, nmap);
        k_scat     <<<G_*4,    1024, 0, stream>>>(row, colp, P.ea, rowptr, colptr,
                                                  rowcsr, colcsr);
        k_gemm_dual<<<NT_/32,  256, 0, stream>>>(P.x, FIN_, P.W1n, P.W1s, P.b1,
                                                 b0, b1buf);
        k_edge1f   <<<NT_/4,   256, 0, stream>>>(rowptr, rowcsr, colptr, colcsr,
                                                 P.coords, b0, nsum, b2buf);
        k_gnstat   <<<G_*8,    256, 0, stream>>>(b1buf, b2buf, deg, statsP, N_, 8, 64);
        k_gnprop   <<<NT_/4,   256, 0, stream>>>(b1buf, b2buf, deg, statsP, P.gn1ms,
                                                 P.gn1w, P.gn1b, nsum, P.acls,
                                                 PT, BkT, b1buf);
        k_topk     <<<G_,      512, 0, stream>>>(b1buf, P.poolp, P.acls, colcsr,
                                                 row, colp, perm, tanhv, nmap,
                                                 cls2, ccsr2, deg2);
        k_s2prop   <<<NP2_/4,  256, 0, stream>>>(rowptr, rowcsr, perm, nmap,
                                                 P.coords, b1buf, tanhv, cls2,
                                                 PT, BkT, b2buf,
                                                 b0 + (size_t)NP2_ * 64);
        k_gemm_dual<<<NP2_/32, 256, 0, stream>>>(b2buf, 64, P.W2n, P.W2s, P.b2,
                                                 b0, b3buf);
        k_gagg2    <<<NP2_/4,  256, 0, stream>>>(colptr, ccsr2, perm, b0, b1buf);
        k_gnstat   <<<G_*6,    256, 0, stream>>>(b3buf, b1buf, deg2, statsP, KP_, 6, 60);
        k_gnrd     <<<G_*6,    256, 0, stream>>>(b3buf, b1buf, deg2, statsP,
                                                 P.gn2ms, P.gn2w, P.gn2b, readP);
        k_rfin     <<<G_,      64,  0, stream>>>(readP, 6, P.l1W, P.l1b,
                                                 P.l2W, P.l2b, (float*)d_out);
    }
}

// Round 13
// 341.743 us; speedup vs baseline: 3.8446x; 3.8446x over previous
//
#include <hip/hip_runtime.h>
#include <math.h>

#define G_    64
#define N_    512
#define NT_   32768
#define ET_   1048576
#define EPG_  16384
#define KP_   359
#define NP2_  22976
#define FIN_  128

// ---------------- fused prep+hist: slices (512) + BkT (96) + PT (6) ----------------
__global__ __launch_bounds__(256)
void k_histprep(const int* __restrict__ row, const int* __restrict__ col,
                int* __restrict__ histR8, int* __restrict__ histC8,
                const float* __restrict__ Bk, const float* __restrict__ posW,
                const float* __restrict__ posb,
                float* __restrict__ BkT, float* __restrict__ PT) {
    int b = blockIdx.x, t = threadIdx.x;
    if (b < 512) {
        __shared__ int hr[N_], hc[N_];
        int g = b >> 3, s = b & 7;
        for (int i = t; i < N_; i += 256) { hr[i] = 0; hc[i] = 0; }
        __syncthreads();
        int ebase = g * EPG_ + s * 2048;
        for (int i = t; i < 2048; i += 256) {
            atomicAdd(&hr[row[ebase + i] & (N_ - 1)], 1);
            atomicAdd(&hc[col[ebase + i] & (N_ - 1)], 1);
        }
        __syncthreads();
        int sbase = b * N_;
        for (int i = t; i < N_; i += 256) {
            histR8[sbase + i] = hr[i];
            histC8[sbase + i] = hc[i];
        }
    } else if (b < 608) {
        int idx = (b - 512) * 256 + t;
        int c = idx >> 12, r = idx & 4095;
        int h = r >> 6, d = r & 63;
        BkT[c*4096 + d*64 + h] = Bk[c*4096 + h*64 + d];
    } else {
        int c = b - 608;
        int i = t >> 6, h = t & 63;
        const float* B = Bk + c*4096 + h*64;
        float acc = 0.f;
        for (int d = 0; d < 64; d++) {
            float vd = (i < 3) ? posW[i*64 + d] : posb[d];
            acc += B[d] * vd;
        }
        PT[c*256 + i*64 + h] = acc;
    }
}

// ---------------- dual GEMM: outA = in@Wa, outB = in@Wb + bias ----------------
__global__ __launch_bounds__(256)
void k_gemm_dual(const float* __restrict__ in, int K,
                 const float* __restrict__ Wa, const float* __restrict__ Wb,
                 const float* __restrict__ bias,
                 float* __restrict__ outA, float* __restrict__ outB) {
    __shared__ float inT[32 * FIN_];
    int row0 = blockIdx.x * 32;
    int t = threadIdx.x;
    for (int idx = t; idx < 32 * K; idx += 256) inT[idx] = in[row0 * K + idx];
    __syncthreads();
    int c = t & 63, rb = t >> 6;
    const float* ip = inT + (rb * 8) * K;
    float aA[8] = {0,0,0,0,0,0,0,0};
    float aB[8] = {0,0,0,0,0,0,0,0};
    for (int k = 0; k < K; k += 4) {
        float wa0 = Wa[(k+0)*64 + c], wa1 = Wa[(k+1)*64 + c];
        float wa2 = Wa[(k+2)*64 + c], wa3 = Wa[(k+3)*64 + c];
        float wb0 = Wb[(k+0)*64 + c], wb1 = Wb[(k+1)*64 + c];
        float wb2 = Wb[(k+2)*64 + c], wb3 = Wb[(k+3)*64 + c];
        #pragma unroll
        for (int r = 0; r < 8; r++) {
            float4 xv = *(const float4*)&ip[r*K + k];
            aA[r] += xv.x*wa0; aB[r] += xv.x*wb0;
            aA[r] += xv.y*wa1; aB[r] += xv.y*wb1;
            aA[r] += xv.z*wa2; aB[r] += xv.z*wb2;
            aA[r] += xv.w*wa3; aB[r] += xv.w*wb3;
        }
    }
    float bv = bias[c];
    #pragma unroll
    for (int r = 0; r < 8; r++) {
        int node = row0 + rb*8 + r;
        outA[node*64 + c] = aA[r];
        outB[node*64 + c] = aB[r] + bv;
    }
}

// ---------------- fused build+edge kernel: scan + scatter + nsum + agg + gn-stats ----
// Block (g,q) owns nodes [q*128,(q+1)*128). It writes ALL csr entries of its owned
// nodes (range-owned scatter), then immediately walks them: nsum (row side), agg
// (col side), and accumulates graph_norm partial stats for its 128 nodes.
__global__ __launch_bounds__(1024)
void k_scatfuse(const int* __restrict__ row, const int* __restrict__ col,
                const float* __restrict__ ea,
                const int* __restrict__ histR8, const int* __restrict__ histC8,
                const float* __restrict__ coords, const float* __restrict__ y,
                const float* __restrict__ hself,
                int2* __restrict__ rowcsr, int* __restrict__ colcsr,
                int* __restrict__ rowptr, int* __restrict__ colptr,
                float* __restrict__ deg, int* __restrict__ nmap,
                float4* __restrict__ nsum, float* __restrict__ agg,
                float* __restrict__ statsP) {
    __shared__ int hr[N_], hc[N_];
    __shared__ int rst[128], rcn[128], cst[128], ccn[128];
    __shared__ float red[2048];
    int g = blockIdx.x >> 2, q = blockIdx.x & 3;
    int t = threadIdx.x;
    int lo = q * 128;
    int nbase = g * N_, ebase = g * EPG_;
    // sum the 8 slice histograms
    for (int i = t; i < N_; i += 1024) {
        int sr = 0, sc = 0;
        #pragma unroll
        for (int s = 0; s < 8; s++) {
            sr += histR8[(g*8 + s)*N_ + i];
            sc += histC8[(g*8 + s)*N_ + i];
        }
        hr[i] = sr; hc[i] = sc;
    }
    __syncthreads();
    // exclusive scan (wave 0: hr, wave 1: hc)
    int wave = t >> 6, lane = t & 63;
    if (wave < 2) {
        int* h = wave ? hc : hr;
        int base8 = lane * 8;
        int loc[8];
        int tot = 0;
        #pragma unroll
        for (int i = 0; i < 8; i++) { int v = h[base8 + i]; loc[i] = tot; tot += v; }
        int pref = tot;
        for (int off = 1; off < 64; off <<= 1) {
            int u = __shfl_up(pref, off);
            if (lane >= off) pref += u;
        }
        pref -= tot;
        #pragma unroll
        for (int i = 0; i < 8; i++) h[base8 + i] = pref + loc[i];
    }
    __syncthreads();
    // capture owned starts/counts; publish ptrs/deg/nmap for owned nodes
    if (t < 128) {
        int i = lo + t;
        int rs = hr[i];
        int re = (i < N_ - 1) ? hr[i + 1] : EPG_;
        int cs = hc[i];
        int ce = (i < N_ - 1) ? hc[i + 1] : EPG_;
        rst[t] = ebase + rs; rcn[t] = re - rs;
        cst[t] = ebase + cs; ccn[t] = ce - cs;
        rowptr[nbase + i] = ebase + rs;
        colptr[nbase + i] = ebase + cs;
        deg[nbase + i] = (float)(ce - cs);
        nmap[nbase + i] = -1;
    }
    if (blockIdx.x == 0 && t == 0) { rowptr[NT_] = ET_; colptr[NT_] = ET_; }
    __syncthreads();
    // range-owned scatter via LDS cursors (hr/hc reused as cursors)
    for (int i = t; i < EPG_; i += 1024) {
        int rg = row[ebase + i];
        int cg = col[ebase + i];
        int rl = (rg & (N_ - 1)) - lo;
        if ((unsigned)rl < 128u) {
            int pr = atomicAdd(&hr[lo + rl], 1);
            rowcsr[ebase + pr] = make_int2(cg, __float_as_int(ea[ebase + i]));
        }
        int cl = (cg & (N_ - 1)) - lo;
        if ((unsigned)cl < 128u) {
            int pc = atomicAdd(&hc[lo + cl], 1);
            colcsr[ebase + pc] = rg;
        }
    }
    __threadfence_block();
    __syncthreads();
    // walk owned nodes: wave w handles nodes lo + w*8 .. lo + w*8+7
    float s1 = 0.f, s2 = 0.f;            // per-lane (=channel) stats accum
    #pragma unroll
    for (int r = 0; r < 8; r++) {
        int li   = wave * 8 + r;         // local owned index
        int node = nbase + lo + li;
        // nsum: lane = edge
        int rs = rst[li], rc = rcn[li];
        float sx = 0.f, sy = 0.f, sz = 0.f, sw = 0.f;
        for (int k = lane; k < rc; k += 64) {
            int2 ent = rowcsr[rs + k];
            int c = ent.x;
            float w = __int_as_float(ent.y);
            sx += w * coords[c*3+0];
            sy += w * coords[c*3+1];
            sz += w * coords[c*3+2];
            sw += w;
        }
        #pragma unroll
        for (int off = 32; off; off >>= 1) {
            sx += __shfl_xor(sx, off); sy += __shfl_xor(sy, off);
            sz += __shfl_xor(sz, off); sw += __shfl_xor(sw, off);
        }
        if (lane == 0) nsum[node] = make_float4(sx, sy, sz, sw);
        // agg: lane = channel
        int cs = cst[li], cc = ccn[li];
        float acc = 0.f;
        #pragma unroll 8
        for (int k = 0; k < cc; k++) {
            int rr = colcsr[cs + k];
            acc += y[rr*64 + lane];
        }
        agg[node*64 + lane] = acc;
        float v = hself[node*64 + lane] + acc / fmaxf((float)cc, 1.f);
        s1 += v; s2 += v * v;
    }
    red[wave*64 + lane]        = s1;
    red[1024 + wave*64 + lane] = s2;
    __syncthreads();
    if (t < 64) {
        float a1 = 0.f, a2 = 0.f;
        #pragma unroll
        for (int wv = 0; wv < 16; wv++) {
            a1 += red[wv*64 + t];
            a2 += red[1024 + wv*64 + t];
        }
        statsP[blockIdx.x*128 + t]      = a1;   // blockIdx.x == g*4+q
        statsP[blockIdx.x*128 + 64 + t] = a2;
    }
}

// ---------------- graph_norm stats (stage 2 only) ----------------
__global__ __launch_bounds__(256)
void k_gnstat(const float* __restrict__ hs, const float* __restrict__ agg,
              const float* __restrict__ deg, float* __restrict__ partial,
              int NPG, int CH, int npc) {
    __shared__ float r1[256], r2[256];
    int b = blockIdx.x;
    int g = b / CH, chunk = b % CH;
    int t = threadIdx.x, c = t & 63, grp = t >> 6;
    int n0 = chunk * npc;
    int nend = min(n0 + npc, NPG);
    float s1 = 0.f, s2 = 0.f;
    for (int n = n0 + grp; n < nend; n += 4) {
        int node = g * NPG + n;
        float v = hs[node*64 + c] + agg[node*64 + c] / fmaxf(deg[node], 1.f);
        s1 += v; s2 += v * v;
    }
    r1[t] = s1; r2[t] = s2;
    __syncthreads();
    if (grp == 0) {
        partial[b*128 + c]      = r1[c] + r1[64+c] + r1[128+c] + r1[192+c];
        partial[b*128 + 64 + c] = r2[c] + r2[64+c] + r2[128+c] + r2[192+c];
    }
}

// ---------------- stage-1 fused: gn-finalize + apply + elu + delta + propagate -------
__global__ __launch_bounds__(256)
void k_gnprop(const float* __restrict__ hself, const float* __restrict__ agg,
              const float* __restrict__ deg, const float* __restrict__ partial,
              const float* __restrict__ ms,
              const float* __restrict__ w, const float* __restrict__ b,
              const float4* __restrict__ nsum, const int* __restrict__ cls,
              const float* __restrict__ PT, const float* __restrict__ BkT,
              float* __restrict__ out) {
    __shared__ float hT[256];
    int t = threadIdx.x;
    int node = blockIdx.x * 4 + (t >> 6);
    int lane = t & 63;
    int g = (blockIdx.x * 4) >> 9;
    float s1 = 0.f, s2 = 0.f;
    #pragma unroll
    for (int i = 0; i < 4; i++) {
        s1 += partial[(g*4 + i)*128 + lane];
        s2 += partial[(g*4 + i)*128 + 64 + lane];
    }
    float m  = s1 / (float)N_, q = s2 / (float)N_, msv = ms[lane];
    float var = q - msv * m * m * (2.f - msv);
    float mval = msv * m;
    float istd = rsqrtf(var + 1e-5f);
    float4 s4 = nsum[node];
    int c = cls[node];
    const float* P = PT + c * 256;
    float d = s4.x*P[lane] + s4.y*P[64+lane] + s4.z*P[128+lane] + s4.w*P[192+lane];
    float v = hself[node*64 + lane] + agg[node*64 + lane] / fmaxf(deg[node], 1.f);
    v = w[lane] * (v - mval) * istd + b[lane];
    v = v > 0.f ? v : expm1f(v);
    v += d;
    hT[t] = v;
    __syncthreads();
    float ssum = v;
    #pragma unroll
    for (int off = 32; off; off >>= 1) ssum += __shfl_xor(ssum, off);
    const float* B  = BkT + c * 4096;
    const float* hv = hT + (t & ~63);
    float acc = 0.f;
    #pragma unroll 8
    for (int j = 0; j < 64; j++) acc += B[j*64 + lane] * hv[j];
    out[node*64 + lane] = acc + d * ssum;
}

// ---------------- top-k per graph + ccsr2 remap + deg2 ----------------
__global__ __launch_bounds__(512)
void k_topk(const float* __restrict__ hp, const float* __restrict__ p,
            const int* __restrict__ cls, const int* __restrict__ ccsr,
            const int* __restrict__ row, const int* __restrict__ col,
            int* __restrict__ perm, float* __restrict__ tanhv,
            int* __restrict__ node_map, int* __restrict__ class2,
            int* __restrict__ ccsr2, float* __restrict__ deg2) {
    __shared__ float key[N_];
    __shared__ int   idxS[N_];
    __shared__ int   lmap[N_];
    __shared__ int   ideg[KP_];
    __shared__ float pS[64];
    __shared__ float nrm;
    int g = blockIdx.x, t = threadIdx.x;
    lmap[t] = -1;
    if (t < 64) pS[t] = p[t];
    for (int i = t; i < KP_; i += 512) ideg[i] = 0;
    __syncthreads();
    if (t == 0) {
        float s = 0.f;
        for (int i = 0; i < 64; i++) s += pS[i] * pS[i];
        nrm = sqrtf(s);
    }
    __syncthreads();
    {
        float acc = 0.f;
        const float* hv = hp + (size_t)(g*N_ + t) * 64;
        for (int cdx = 0; cdx < 64; cdx++) acc += hv[cdx] * pS[cdx];
        key[t]  = acc / nrm;
        idxS[t] = t;
    }
    __syncthreads();
    for (int k = 2; k <= N_; k <<= 1) {
        for (int j = k >> 1; j > 0; j >>= 1) {
            int i = t, ixj = i ^ j;
            if (ixj > i) {
                float ki = key[i], kj = key[ixj];
                int   ii = idxS[i], ij = idxS[ixj];
                bool before = (ki > kj) || (ki == kj && ii < ij);
                bool dir = ((i & k) == 0);
                if (dir ? !before : before) {
                    key[i] = kj; key[ixj] = ki;
                    idxS[i] = ij; idxS[ixj] = ii;
                }
            }
            __syncthreads();
        }
    }
    if (t < KP_) {
        int orig  = idxS[t];
        int gnode = g * N_ + orig;
        int pj    = g * KP_ + t;
        perm[pj]     = gnode;
        tanhv[pj]    = tanhf(key[t]);
        node_map[gnode] = pj;
        class2[pj]   = cls[gnode];
        lmap[orig]   = pj;
    }
    __syncthreads();
    int ebase = g * EPG_;
    for (int k = t; k < EPG_; k += 512) {
        int mm = lmap[ccsr[ebase + k] & (N_ - 1)];
        ccsr2[ebase + k] = (mm >= 0) ? mm : NP2_;
    }
    for (int k = t; k < EPG_; k += 512) {
        int mr = lmap[row[ebase + k] & (N_ - 1)];
        int mc = lmap[col[ebase + k] & (N_ - 1)];
        if (mr >= 0 && mc >= 0) atomicAdd(&ideg[mc - g * KP_], 1);
    }
    __syncthreads();
    for (int i = t; i < KP_; i += 512) deg2[g * KP_ + i] = (float)ideg[i];
}

// ---------------- fused stage-2: masked sums + gather*tanh + delta2 + propagate ------
__global__ __launch_bounds__(256)
void k_s2prop(const int* __restrict__ rowptr, const int2* __restrict__ rcsr,
              const int* __restrict__ perm, const int* __restrict__ nmap,
              const float* __restrict__ coords,
              const float* __restrict__ hp, const float* __restrict__ tanhv,
              const int* __restrict__ cls2,
              const float* __restrict__ PT, const float* __restrict__ BkT,
              float* __restrict__ out, float* __restrict__ y2zero) {
    __shared__ float hT[256];
    int t = threadIdx.x;
    int j = blockIdx.x * 4 + (t >> 6);
    int lane = t & 63;
    if (blockIdx.x == 0 && t < 64) y2zero[t] = 0.f;
    int orig = perm[j];
    int rs = rowptr[orig], re = rowptr[orig + 1];
    float sx = 0.f, sy = 0.f, sz = 0.f, sw = 0.f;
    for (int k = rs + lane; k < re; k += 64) {
        int c = rcsr[k].x;
        if (nmap[c] >= 0) {
            sx += coords[c*3+0]; sy += coords[c*3+1]; sz += coords[c*3+2];
            sw += 1.f;
        }
    }
    #pragma unroll
    for (int off = 32; off; off >>= 1) {
        sx += __shfl_xor(sx, off); sy += __shfl_xor(sy, off);
        sz += __shfl_xor(sz, off); sw += __shfl_xor(sw, off);
    }
    int c = cls2[j];
    const float* P = PT + c * 256;
    float d = sx*P[lane] + sy*P[64+lane] + sz*P[128+lane] + sw*P[192+lane];
    float v = hp[orig*64 + lane] * tanhv[j] + d;
    hT[t] = v;
    __syncthreads();
    float ssum = v;
    #pragma unroll
    for (int off = 32; off; off >>= 1) ssum += __shfl_xor(ssum, off);
    const float* B  = BkT + c * 4096;
    const float* hv = hT + (t & ~63);
    float acc = 0.f;
    #pragma unroll 8
    for (int jj = 0; jj < 64; jj++) acc += B[jj*64 + lane] * hv[jj];
    out[j*64 + lane] = acc + d * ssum;
}

// ---------------- stage-2 agg gather via remapped ccsr2 ----------------
__global__ __launch_bounds__(256)
void k_gagg2(const int* __restrict__ colptr, const int* __restrict__ ccsr2,
             const int* __restrict__ perm, const float* __restrict__ y2,
             float* __restrict__ agg2) {
    int j = blockIdx.x * 4 + (threadIdx.x >> 6);
    int lane = threadIdx.x & 63;
    int orig = perm[j];
    int start = colptr[orig], end = colptr[orig + 1];
    float acc = 0.f;
    #pragma unroll 8
    for (int k = start; k < end; k++) {
        int r = ccsr2[k];
        acc += y2[r*64 + lane];
    }
    agg2[j*64 + lane] = acc;
}

// ---------------- fused stage-2 gn-finalize + apply + elu + readout partials ---------
__global__ __launch_bounds__(256)
void k_gnrd(const float* __restrict__ hs, const float* __restrict__ agg,
            const float* __restrict__ deg2, const float* __restrict__ statsP,
            const float* __restrict__ ms,
            const float* __restrict__ w, const float* __restrict__ b,
            float* __restrict__ readP) {
    __shared__ float r1[256], r2[256];
    int blk = blockIdx.x;
    int g = blk / 6, chunk = blk % 6;
    int t = threadIdx.x, c = t & 63, grp = t >> 6;
    float s1 = 0.f, s2 = 0.f;
    #pragma unroll
    for (int i = 0; i < 6; i++) {
        s1 += statsP[(g*6 + i)*128 + c];
        s2 += statsP[(g*6 + i)*128 + 64 + c];
    }
    float mean = s1 / (float)KP_, q = s2 / (float)KP_, msv = ms[c];
    float var = q - msv * mean * mean * (2.f - msv);
    float mv = msv * mean;
    float is = rsqrtf(var + 1e-5f);
    float wv = w[c], bv = b[c];
    int n0 = chunk * 60, nend = min(n0 + 60, KP_);
    float s = 0.f, m = -1e30f;
    for (int n = n0 + grp; n < nend; n += 4) {
        int node = g * KP_ + n;
        float v = hs[node*64 + c] + agg[node*64 + c] / fmaxf(deg2[node], 1.f);
        v = wv * (v - mv) * is + bv;
        v = v > 0.f ? v : expm1f(v);
        s += v; m = fmaxf(m, v);
    }
    r1[t] = s; r2[t] = m;
    __syncthreads();
    if (grp == 0) {
        readP[blk*128 + c]      = r1[c] + r1[64+c] + r1[128+c] + r1[192+c];
        readP[blk*128 + 64 + c] = fmaxf(fmaxf(r2[c], r2[64+c]), fmaxf(r2[128+c], r2[192+c]));
    }
}

// ---------------- readout finalize ----------------
__global__ void k_rfin(const float* __restrict__ part, int CH,
                       const float* __restrict__ l1W, const float* __restrict__ l1b,
                       const float* __restrict__ l2W, const float* __restrict__ l2b,
                       float* __restrict__ out) {
    __shared__ float gv[192], rS[64];
    int g = blockIdx.x, t = threadIdx.x;
    float s = 0.f, m = -1e30f;
    for (int i = 0; i < CH; i++) {
        s += part[(g*CH + i)*128 + t];
        m = fmaxf(m, part[(g*CH + i)*128 + 64 + t]);
    }
    gv[t] = s / (float)KP_;
    gv[64 + t] = m;
    gv[128 + t] = s;
    __syncthreads();
    float acc = l1b[t];
    for (int k = 0; k < 192; k++) acc += gv[k] * l1W[k*64 + t];
    rS[t] = fmaxf(acc, 0.f);
    __syncthreads();
    if (t == 0) {
        float l0 = l2b[0], l1v = l2b[1];
        for (int hh = 0; hh < 64; hh++) { l0 += rS[hh]*l2W[hh*2+0]; l1v += rS[hh]*l2W[hh*2+1]; }
        float mx  = fmaxf(l0, l1v);
        float lse = mx + logf(expf(l0 - mx) + expf(l1v - mx));
        out[g*2 + 0] = l0  - lse;
        out[g*2 + 1] = l1v - lse;
    }
}

extern "C" void kernel_launch(void* const* d_in, const int* in_sizes, int n_in,
                              void* d_out, int out_size, void* d_ws, size_t ws_size,
                              hipStream_t stream) {
    const float* x      = (const float*)d_in[0];
    const int*   eidx   = (const int*)  d_in[1];
    const float* eattr  = (const float*)d_in[2];
    const float* coords = (const float*)d_in[3];
    const int*   acls   = (const int*)  d_in[4];
    const float* BkTab  = (const float*)d_in[5];
    const float* posW   = (const float*)d_in[6];
    const float* posb   = (const float*)d_in[7];
    const float* W1s    = (const float*)d_in[8];
    const float* W1n    = (const float*)d_in[9];
    const float* b1     = (const float*)d_in[10];
    const float* gn1w   = (const float*)d_in[11];
    const float* gn1b   = (const float*)d_in[12];
    const float* gn1ms  = (const float*)d_in[13];
    const float* poolp  = (const float*)d_in[14];
    const float* W2s    = (const float*)d_in[15];
    const float* W2n    = (const float*)d_in[16];
    const float* b2     = (const float*)d_in[17];
    const float* gn2w   = (const float*)d_in[18];
    const float* gn2b   = (const float*)d_in[19];
    const float* gn2ms  = (const float*)d_in[20];
    const float* l1W    = (const float*)d_in[21];
    const float* l1b    = (const float*)d_in[22];
    const float* l2W    = (const float*)d_in[23];
    const float* l2b    = (const float*)d_in[24];

    const int* row  = eidx;
    const int* colp = eidx + ET_;

    float* W = (float*)d_ws;
    const size_t NTH = (size_t)NT_ * 64;
    float* b0    = W;                           // y -> y2 compact (+zero row NP2_)
    float* b1buf = W + 1*NTH;                   // hself -> hp(in-place) -> agg2
    float* b2buf = W + 2*NTH;                   // agg -> hp2
    float* b3buf = W + 3*NTH;                   // nsum -> hs2
    float* p = W + 4*NTH;
    int2*  rowcsr = (int2*)p;        p += 2*(size_t)ET_;
    int*   colcsr = (int*)p;         p += ET_;
    int*   ccsr2  = (int*)p;         p += ET_;
    int*   rowptr = (int*)p;         p += NT_ + 8;
    int*   colptr = (int*)p;         p += NT_ + 8;
    int*   histR8 = (int*)p;         p += NT_ * 8;
    int*   histC8 = (int*)p;         p += NT_ * 8;
    float* deg    = p;               p += NT_;
    float* deg2   = p;               p += NP2_;
    float* tanhv  = p;               p += NP2_;
    int*   perm   = (int*)p;         p += NP2_;
    int*   nmap   = (int*)p;         p += NT_;
    int*   cls2   = (int*)p;         p += NP2_;
    float* BkT    = p;               p += 6 * 4096;
    float* PT     = p;               p += 6 * 256;
    float* statsP = p;               p += (size_t)G_ * 8 * 128;
    float* readP  = p;               p += (size_t)G_ * 6 * 128;
    float4* nsum  = (float4*)b3buf;             // stage-1 (live scatfuse..gnprop)

    // ---- build + stage 1 ----
    k_histprep <<<614,     256,  0, stream>>>(row, colp, histR8, histC8,
                                              BkTab, posW, posb, BkT, PT);
    k_gemm_dual<<<NT_/32,  256, 0, stream>>>(x, FIN_, W1n, W1s, b1,
                                             b0 /*y*/, b1buf /*hself*/);
    k_scatfuse <<<G_*4,    1024, 0, stream>>>(row, colp, eattr, histR8, histC8,
                                              coords, b0 /*y*/, b1buf /*hself*/,
                                              rowcsr, colcsr, rowptr, colptr,
                                              deg, nmap, nsum, b2buf /*agg*/,
                                              statsP);
    k_gnprop   <<<NT_/4,   256, 0, stream>>>(b1buf /*hself*/, b2buf /*agg*/, deg,
                                             statsP, gn1ms, gn1w, gn1b,
                                             nsum, acls, PT, BkT,
                                             b1buf /*hp in-place*/);
    k_topk     <<<G_,      512, 0, stream>>>(b1buf /*hp*/, poolp, acls, colcsr,
                                             row, colp, perm, tanhv, nmap,
                                             cls2, ccsr2, deg2);

    // ---- stage 2 ----
    k_s2prop   <<<NP2_/4,  256, 0, stream>>>(rowptr, rowcsr, perm, nmap, coords,
                                             b1buf /*hp*/, tanhv, cls2, PT, BkT,
                                             b2buf /*hp2*/,
                                             b0 + (size_t)NP2_ * 64 /*zero row*/);
    k_gemm_dual<<<NP2_/32, 256, 0, stream>>>(b2buf /*hp2*/, 64, W2n, W2s, b2,
                                             b0 /*y2 compact*/, b3buf /*hs2*/);
    k_gagg2    <<<NP2_/4,  256, 0, stream>>>(colptr, ccsr2, perm, b0 /*y2*/,
                                             b1buf /*agg2*/);
    k_gnstat   <<<G_*6,    256, 0, stream>>>(b3buf /*hs2*/, b1buf /*agg2*/, deg2,
                                             statsP, KP_, 6, 60);
    k_gnrd     <<<G_*6,    256, 0, stream>>>(b3buf /*hs2*/, b1buf /*agg2*/, deg2,
                                             statsP, gn2ms, gn2w, gn2b, readP);
    k_rfin     <<<G_,      64,  0, stream>>>(readP, 6, l1W, l1b, l2W, l2b,
                                             (float*)d_out);
}

// Round 14
// 330.656 us; speedup vs baseline: 3.9735x; 1.0335x over previous
//
#include <hip/hip_runtime.h>
#include <math.h>

#define G_    64
#define N_    512
#define NT_   32768
#define ET_   1048576
#define EPG_  16384
#define KP_   359
#define NP2_  22976
#define FIN_  128

// dual GEMM unit: 32 rows, outA = in@Wa, outB = in@Wb + bias
__device__ __forceinline__
void gemm_unit(int unit, const float* __restrict__ in, int K,
               const float* __restrict__ Wa, const float* __restrict__ Wb,
               const float* __restrict__ bias,
               float* __restrict__ outA, float* __restrict__ outB,
               float* inT, int t) {
    int row0 = unit * 32;
    for (int idx = t; idx < 32 * K; idx += 256) inT[idx] = in[row0 * K + idx];
    __syncthreads();
    int c = t & 63, rb = t >> 6;
    const float* ip = inT + (rb * 8) * K;
    float aA[8] = {0,0,0,0,0,0,0,0};
    float aB[8] = {0,0,0,0,0,0,0,0};
    for (int k = 0; k < K; k += 4) {
        float wa0 = Wa[(k+0)*64 + c], wa1 = Wa[(k+1)*64 + c];
        float wa2 = Wa[(k+2)*64 + c], wa3 = Wa[(k+3)*64 + c];
        float wb0 = Wb[(k+0)*64 + c], wb1 = Wb[(k+1)*64 + c];
        float wb2 = Wb[(k+2)*64 + c], wb3 = Wb[(k+3)*64 + c];
        #pragma unroll
        for (int r = 0; r < 8; r++) {
            float4 xv = *(const float4*)&ip[r*K + k];
            aA[r] += xv.x*wa0; aB[r] += xv.x*wb0;
            aA[r] += xv.y*wa1; aB[r] += xv.y*wb1;
            aA[r] += xv.z*wa2; aB[r] += xv.z*wb2;
            aA[r] += xv.w*wa3; aB[r] += xv.w*wb3;
        }
    }
    float bv = bias[c];
    #pragma unroll
    for (int r = 0; r < 8; r++) {
        int node = row0 + rb*8 + r;
        outA[node*64 + c] = aA[r];
        outB[node*64 + c] = aB[r] + bv;
    }
}

// ---------------- fused roots: stage-1 GEMM (1024) + hist (512) + BkT (96) + PT (6) --
__global__ __launch_bounds__(256)
void k_pregemm(const float* __restrict__ x,
               const float* __restrict__ W1n, const float* __restrict__ W1s,
               const float* __restrict__ b1,
               float* __restrict__ y, float* __restrict__ hself,
               const int* __restrict__ row, const int* __restrict__ col,
               int* __restrict__ histR8, int* __restrict__ histC8,
               const float* __restrict__ Bk, const float* __restrict__ posW,
               const float* __restrict__ posb,
               float* __restrict__ BkT, float* __restrict__ PT) {
    __shared__ float smem[32 * FIN_];    // 16 KB (gemm); hist uses first 4 KB as ints
    int b = blockIdx.x, t = threadIdx.x;
    if (b < NT_/32) {
        gemm_unit(b, x, FIN_, W1n, W1s, b1, y, hself, smem, t);
    } else if (b < NT_/32 + 512) {
        int bb = b - NT_/32;
        int* hr = (int*)smem; int* hc = hr + N_;
        int g = bb >> 3, s = bb & 7;
        for (int i = t; i < N_; i += 256) { hr[i] = 0; hc[i] = 0; }
        __syncthreads();
        int ebase = g * EPG_ + s * 2048;
        for (int i = t; i < 2048; i += 256) {
            atomicAdd(&hr[row[ebase + i] & (N_ - 1)], 1);
            atomicAdd(&hc[col[ebase + i] & (N_ - 1)], 1);
        }
        __syncthreads();
        int sbase = bb * N_;
        for (int i = t; i < N_; i += 256) {
            histR8[sbase + i] = hr[i];
            histC8[sbase + i] = hc[i];
        }
    } else if (b < NT_/32 + 608) {
        int idx = (b - NT_/32 - 512) * 256 + t;
        int c = idx >> 12, r = idx & 4095;
        int h = r >> 6, d = r & 63;
        BkT[c*4096 + d*64 + h] = Bk[c*4096 + h*64 + d];
    } else {
        int c = b - (NT_/32 + 608);
        int i = t >> 6, h = t & 63;
        const float* B = Bk + c*4096 + h*64;
        float acc = 0.f;
        for (int d = 0; d < 64; d++) {
            float vd = (i < 3) ? posW[i*64 + d] : posb[d];
            acc += B[d] * vd;
        }
        PT[c*256 + i*64 + h] = acc;
    }
}

// ---------------- scan + range-owned CSR scatter (G*4 blocks, 128-node ranges) -------
__global__ __launch_bounds__(1024)
void k_scatscan(const int* __restrict__ row, const int* __restrict__ col,
                const float* __restrict__ ea,
                const int* __restrict__ histR8, const int* __restrict__ histC8,
                int2* __restrict__ rowcsr, int* __restrict__ colcsr,
                int* __restrict__ rowptr, int* __restrict__ colptr,
                int* __restrict__ nmap) {
    __shared__ int hr[N_], hc[N_];
    int g = blockIdx.x >> 2, q = blockIdx.x & 3;
    int t = threadIdx.x;
    int lo = q * 128;
    int nbase = g * N_, ebase = g * EPG_;
    for (int i = t; i < N_; i += 1024) {
        int sr = 0, sc = 0;
        #pragma unroll
        for (int s = 0; s < 8; s++) {
            sr += histR8[(g*8 + s)*N_ + i];
            sc += histC8[(g*8 + s)*N_ + i];
        }
        hr[i] = sr; hc[i] = sc;
    }
    __syncthreads();
    int wave = t >> 6, lane = t & 63;
    if (wave < 2) {
        int* h = wave ? hc : hr;
        int base8 = lane * 8;
        int loc[8];
        int tot = 0;
        #pragma unroll
        for (int i = 0; i < 8; i++) { int v = h[base8 + i]; loc[i] = tot; tot += v; }
        int pref = tot;
        for (int off = 1; off < 64; off <<= 1) {
            int u = __shfl_up(pref, off);
            if (lane >= off) pref += u;
        }
        pref -= tot;
        #pragma unroll
        for (int i = 0; i < 8; i++) h[base8 + i] = pref + loc[i];
    }
    __syncthreads();
    if (t < 128) {
        int i = lo + t;
        rowptr[nbase + i] = ebase + hr[i];
        colptr[nbase + i] = ebase + hc[i];
        nmap[nbase + i] = -1;
    }
    if (blockIdx.x == 0 && t == 0) { rowptr[NT_] = ET_; colptr[NT_] = ET_; }
    __syncthreads();
    for (int i = t; i < EPG_; i += 1024) {
        int rg = row[ebase + i];
        int cg = col[ebase + i];
        int rl = (rg & (N_ - 1)) - lo;
        if ((unsigned)rl < 128u) {
            int pr = atomicAdd(&hr[lo + rl], 1);
            rowcsr[ebase + pr] = make_int2(cg, __float_as_int(ea[ebase + i]));
        }
        int cl = (cg & (N_ - 1)) - lo;
        if ((unsigned)cl < 128u) {
            int pc = atomicAdd(&hc[lo + cl], 1);
            colcsr[ebase + pc] = rg;
        }
    }
}

// ---------------- wide edge pulls: nsum + vbuf (= hself + agg/deg) -------------------
__global__ __launch_bounds__(256)
void k_edge1f(const int* __restrict__ rowptr, const int2* __restrict__ rcsr,
              const int* __restrict__ colptr, const int* __restrict__ ccsr,
              const float* __restrict__ coords, const float* __restrict__ y,
              const float* __restrict__ hself,
              float4* __restrict__ nsum, float* __restrict__ vbuf) {
    int node = blockIdx.x * 4 + (threadIdx.x >> 6);
    int lane = threadIdx.x & 63;
    int rs = rowptr[node], re = rowptr[node + 1];
    float sx = 0.f, sy = 0.f, sz = 0.f, sw = 0.f;
    for (int k = rs + lane; k < re; k += 64) {
        int2 ent = rcsr[k];
        int c = ent.x;
        float w = __int_as_float(ent.y);
        sx += w * coords[c*3+0];
        sy += w * coords[c*3+1];
        sz += w * coords[c*3+2];
        sw += w;
    }
    #pragma unroll
    for (int off = 32; off; off >>= 1) {
        sx += __shfl_xor(sx, off); sy += __shfl_xor(sy, off);
        sz += __shfl_xor(sz, off); sw += __shfl_xor(sw, off);
    }
    if (lane == 0) nsum[node] = make_float4(sx, sy, sz, sw);
    int cs = colptr[node], ce = colptr[node + 1];
    float acc = 0.f;
    #pragma unroll 8
    for (int k = cs; k < ce; k++) {
        int r = ccsr[k];
        acc += y[r*64 + lane];
    }
    vbuf[node*64 + lane] = hself[node*64 + lane] + acc / fmaxf((float)(ce - cs), 1.f);
}

// ---------------- graph_norm stats over a precomputed v array ----------------
__global__ __launch_bounds__(256)
void k_gnstat(const float* __restrict__ v, float* __restrict__ partial,
              int NPG, int CH, int npc) {
    __shared__ float r1[256], r2[256];
    int b = blockIdx.x;
    int g = b / CH, chunk = b % CH;
    int t = threadIdx.x, c = t & 63, grp = t >> 6;
    int n0 = chunk * npc;
    int nend = min(n0 + npc, NPG);
    float s1 = 0.f, s2 = 0.f;
    for (int n = n0 + grp; n < nend; n += 4) {
        float vv = v[(g * NPG + n)*64 + c];
        s1 += vv; s2 += vv * vv;
    }
    r1[t] = s1; r2[t] = s2;
    __syncthreads();
    if (grp == 0) {
        partial[b*128 + c]      = r1[c] + r1[64+c] + r1[128+c] + r1[192+c];
        partial[b*128 + 64 + c] = r2[c] + r2[64+c] + r2[128+c] + r2[192+c];
    }
}

// ---------------- stage-1 fused: gn-finalize + apply + elu + delta + propagate -------
__global__ __launch_bounds__(256)
void k_gnprop(const float* __restrict__ vbuf, const float* __restrict__ partial,
              const float* __restrict__ ms,
              const float* __restrict__ w, const float* __restrict__ b,
              const float4* __restrict__ nsum, const int* __restrict__ cls,
              const float* __restrict__ PT, const float* __restrict__ BkT,
              float* __restrict__ out) {
    __shared__ float hT[256];
    int t = threadIdx.x;
    int node = blockIdx.x * 4 + (t >> 6);
    int lane = t & 63;
    int g = (blockIdx.x * 4) >> 9;
    float s1 = 0.f, s2 = 0.f;
    #pragma unroll
    for (int i = 0; i < 8; i++) {
        s1 += partial[(g*8 + i)*128 + lane];
        s2 += partial[(g*8 + i)*128 + 64 + lane];
    }
    float m  = s1 / (float)N_, q = s2 / (float)N_, msv = ms[lane];
    float var = q - msv * m * m * (2.f - msv);
    float mval = msv * m;
    float istd = rsqrtf(var + 1e-5f);
    float4 s4 = nsum[node];
    int c = cls[node];
    const float* P = PT + c * 256;
    float d = s4.x*P[lane] + s4.y*P[64+lane] + s4.z*P[128+lane] + s4.w*P[192+lane];
    float v = vbuf[node*64 + lane];
    v = w[lane] * (v - mval) * istd + b[lane];
    v = v > 0.f ? v : expm1f(v);
    v += d;
    hT[t] = v;
    __syncthreads();
    float ssum = v;
    #pragma unroll
    for (int off = 32; off; off >>= 1) ssum += __shfl_xor(ssum, off);
    const float* B  = BkT + c * 4096;
    const float* hv = hT + (t & ~63);
    float acc = 0.f;
    #pragma unroll 8
    for (int j = 0; j < 64; j++) acc += B[j*64 + lane] * hv[j];
    out[node*64 + lane] = acc + d * ssum;
}

// ---------------- top-k per graph + ccsr2 remap + deg2 ----------------
__global__ __launch_bounds__(512)
void k_topk(const float* __restrict__ hp, const float* __restrict__ p,
            const int* __restrict__ cls, const int* __restrict__ ccsr,
            const int* __restrict__ row, const int* __restrict__ col,
            int* __restrict__ perm, float* __restrict__ tanhv,
            int* __restrict__ node_map, int* __restrict__ class2,
            int* __restrict__ ccsr2, float* __restrict__ deg2) {
    __shared__ float key[N_];
    __shared__ int   idxS[N_];
    __shared__ int   lmap[N_];
    __shared__ int   ideg[KP_];
    __shared__ float pS[64];
    __shared__ float nrm;
    int g = blockIdx.x, t = threadIdx.x;
    lmap[t] = -1;
    if (t < 64) pS[t] = p[t];
    for (int i = t; i < KP_; i += 512) ideg[i] = 0;
    __syncthreads();
    if (t == 0) {
        float s = 0.f;
        for (int i = 0; i < 64; i++) s += pS[i] * pS[i];
        nrm = sqrtf(s);
    }
    __syncthreads();
    {
        float acc = 0.f;
        const float* hv = hp + (size_t)(g*N_ + t) * 64;
        for (int cdx = 0; cdx < 64; cdx++) acc += hv[cdx] * pS[cdx];
        key[t]  = acc / nrm;
        idxS[t] = t;
    }
    __syncthreads();
    for (int k = 2; k <= N_; k <<= 1) {
        for (int j = k >> 1; j > 0; j >>= 1) {
            int i = t, ixj = i ^ j;
            if (ixj > i) {
                float ki = key[i], kj = key[ixj];
                int   ii = idxS[i], ij = idxS[ixj];
                bool before = (ki > kj) || (ki == kj && ii < ij);
                bool dir = ((i & k) == 0);
                if (dir ? !before : before) {
                    key[i] = kj; key[ixj] = ki;
                    idxS[i] = ij; idxS[ixj] = ii;
                }
            }
            __syncthreads();
        }
    }
    if (t < KP_) {
        int orig  = idxS[t];
        int gnode = g * N_ + orig;
        int pj    = g * KP_ + t;
        perm[pj]     = gnode;
        tanhv[pj]    = tanhf(key[t]);
        node_map[gnode] = pj;
        class2[pj]   = cls[gnode];
        lmap[orig]   = pj;
    }
    __syncthreads();
    int ebase = g * EPG_;
    for (int k = t; k < EPG_; k += 512) {
        int mm = lmap[ccsr[ebase + k] & (N_ - 1)];
        ccsr2[ebase + k] = (mm >= 0) ? mm : NP2_;
    }
    for (int k = t; k < EPG_; k += 512) {
        int mr = lmap[row[ebase + k] & (N_ - 1)];
        int mc = lmap[col[ebase + k] & (N_ - 1)];
        if (mr >= 0 && mc >= 0) atomicAdd(&ideg[mc - g * KP_], 1);
    }
    __syncthreads();
    for (int i = t; i < KP_; i += 512) deg2[g * KP_ + i] = (float)ideg[i];
}

// ---------------- fused stage-2: masked sums + gather*tanh + delta2 + propagate ------
__global__ __launch_bounds__(256)
void k_s2prop(const int* __restrict__ rowptr, const int2* __restrict__ rcsr,
              const int* __restrict__ perm, const int* __restrict__ nmap,
              const float* __restrict__ coords,
              const float* __restrict__ hp, const float* __restrict__ tanhv,
              const int* __restrict__ cls2,
              const float* __restrict__ PT, const float* __restrict__ BkT,
              float* __restrict__ out, float* __restrict__ y2zero) {
    __shared__ float hT[256];
    int t = threadIdx.x;
    int j = blockIdx.x * 4 + (t >> 6);
    int lane = t & 63;
    if (blockIdx.x == 0 && t < 64) y2zero[t] = 0.f;
    int orig = perm[j];
    int rs = rowptr[orig], re = rowptr[orig + 1];
    float sx = 0.f, sy = 0.f, sz = 0.f, sw = 0.f;
    for (int k = rs + lane; k < re; k += 64) {
        int c = rcsr[k].x;
        if (nmap[c] >= 0) {
            sx += coords[c*3+0]; sy += coords[c*3+1]; sz += coords[c*3+2];
            sw += 1.f;
        }
    }
    #pragma unroll
    for (int off = 32; off; off >>= 1) {
        sx += __shfl_xor(sx, off); sy += __shfl_xor(sy, off);
        sz += __shfl_xor(sz, off); sw += __shfl_xor(sw, off);
    }
    int c = cls2[j];
    const float* P = PT + c * 256;
    float d = sx*P[lane] + sy*P[64+lane] + sz*P[128+lane] + sw*P[192+lane];
    float v = hp[orig*64 + lane] * tanhv[j] + d;
    hT[t] = v;
    __syncthreads();
    float ssum = v;
    #pragma unroll
    for (int off = 32; off; off >>= 1) ssum += __shfl_xor(ssum, off);
    const float* B  = BkT + c * 4096;
    const float* hv = hT + (t & ~63);
    float acc = 0.f;
    #pragma unroll 8
    for (int jj = 0; jj < 64; jj++) acc += B[jj*64 + lane] * hv[jj];
    out[j*64 + lane] = acc + d * ssum;
}

// ---------------- stage-2 dual GEMM ----------------
__global__ __launch_bounds__(256)
void k_gemm2(const float* __restrict__ in,
             const float* __restrict__ Wa, const float* __restrict__ Wb,
             const float* __restrict__ bias,
             float* __restrict__ outA, float* __restrict__ outB) {
    __shared__ float inT[32 * 64];
    gemm_unit(blockIdx.x, in, 64, Wa, Wb, bias, outA, outB, inT, threadIdx.x);
}

// ---------------- stage-2 gather -> v2buf (= hs2 + agg2/deg2) ----------------
__global__ __launch_bounds__(256)
void k_gagg2v(const int* __restrict__ colptr, const int* __restrict__ ccsr2,
              const int* __restrict__ perm, const float* __restrict__ y2,
              const float* __restrict__ hs2, const float* __restrict__ deg2,
              float* __restrict__ v2buf) {
    int j = blockIdx.x * 4 + (threadIdx.x >> 6);
    int lane = threadIdx.x & 63;
    int orig = perm[j];
    int start = colptr[orig], end = colptr[orig + 1];
    float acc = 0.f;
    #pragma unroll 8
    for (int k = start; k < end; k++) {
        int r = ccsr2[k];
        acc += y2[r*64 + lane];
    }
    v2buf[j*64 + lane] = hs2[j*64 + lane] + acc / fmaxf(deg2[j], 1.f);
}

// ---------------- fused stage-2 gn-finalize + apply + elu + readout partials ---------
__global__ __launch_bounds__(256)
void k_gnrd(const float* __restrict__ v2, const float* __restrict__ statsP,
            const float* __restrict__ ms,
            const float* __restrict__ w, const float* __restrict__ b,
            float* __restrict__ readP) {
    __shared__ float r1[256], r2[256];
    int blk = blockIdx.x;
    int g = blk / 6, chunk = blk % 6;
    int t = threadIdx.x, c = t & 63, grp = t >> 6;
    float s1 = 0.f, s2 = 0.f;
    #pragma unroll
    for (int i = 0; i < 6; i++) {
        s1 += statsP[(g*6 + i)*128 + c];
        s2 += statsP[(g*6 + i)*128 + 64 + c];
    }
    float mean = s1 / (float)KP_, q = s2 / (float)KP_, msv = ms[c];
    float var = q - msv * mean * mean * (2.f - msv);
    float mv = msv * mean;
    float is = rsqrtf(var + 1e-5f);
    float wv = w[c], bv = b[c];
    int n0 = chunk * 60, nend = min(n0 + 60, KP_);
    float s = 0.f, m = -1e30f;
    for (int n = n0 + grp; n < nend; n += 4) {
        float v = v2[(g * KP_ + n)*64 + c];
        v = wv * (v - mv) * is + bv;
        v = v > 0.f ? v : expm1f(v);
        s += v; m = fmaxf(m, v);
    }
    r1[t] = s; r2[t] = m;
    __syncthreads();
    if (grp == 0) {
        readP[blk*128 + c]      = r1[c] + r1[64+c] + r1[128+c] + r1[192+c];
        readP[blk*128 + 64 + c] = fmaxf(fmaxf(r2[c], r2[64+c]), fmaxf(r2[128+c], r2[192+c]));
    }
}

// ---------------- readout finalize ----------------
__global__ void k_rfin(const float* __restrict__ part, int CH,
                       const float* __restrict__ l1W, const float* __restrict__ l1b,
                       const float* __restrict__ l2W, const float* __restrict__ l2b,
                       float* __restrict__ out) {
    __shared__ float gv[192], rS[64];
    int g = blockIdx.x, t = threadIdx.x;
    float s = 0.f, m = -1e30f;
    for (int i = 0; i < CH; i++) {
        s += part[(g*CH + i)*128 + t];
        m = fmaxf(m, part[(g*CH + i)*128 + 64 + t]);
    }
    gv[t] = s / (float)KP_;
    gv[64 + t] = m;
    gv[128 + t] = s;
    __syncthreads();
    float acc = l1b[t];
    for (int k = 0; k < 192; k++) acc += gv[k] * l1W[k*64 + t];
    rS[t] = fmaxf(acc, 0.f);
    __syncthreads();
    if (t == 0) {
        float l0 = l2b[0], l1v = l2b[1];
        for (int hh = 0; hh < 64; hh++) { l0 += rS[hh]*l2W[hh*2+0]; l1v += rS[hh]*l2W[hh*2+1]; }
        float mx  = fmaxf(l0, l1v);
        float lse = mx + logf(expf(l0 - mx) + expf(l1v - mx));
        out[g*2 + 0] = l0  - lse;
        out[g*2 + 1] = l1v - lse;
    }
}

extern "C" void kernel_launch(void* const* d_in, const int* in_sizes, int n_in,
                              void* d_out, int out_size, void* d_ws, size_t ws_size,
                              hipStream_t stream) {
    const float* x      = (const float*)d_in[0];
    const int*   eidx   = (const int*)  d_in[1];
    const float* eattr  = (const float*)d_in[2];
    const float* coords = (const float*)d_in[3];
    const int*   acls   = (const int*)  d_in[4];
    const float* BkTab  = (const float*)d_in[5];
    const float* posW   = (const float*)d_in[6];
    const float* posb   = (const float*)d_in[7];
    const float* W1s    = (const float*)d_in[8];
    const float* W1n    = (const float*)d_in[9];
    const float* b1     = (const float*)d_in[10];
    const float* gn1w   = (const float*)d_in[11];
    const float* gn1b   = (const float*)d_in[12];
    const float* gn1ms  = (const float*)d_in[13];
    const float* poolp  = (const float*)d_in[14];
    const float* W2s    = (const float*)d_in[15];
    const float* W2n    = (const float*)d_in[16];
    const float* b2     = (const float*)d_in[17];
    const float* gn2w   = (const float*)d_in[18];
    const float* gn2b   = (const float*)d_in[19];
    const float* gn2ms  = (const float*)d_in[20];
    const float* l1W    = (const float*)d_in[21];
    const float* l1b    = (const float*)d_in[22];
    const float* l2W    = (const float*)d_in[23];
    const float* l2b    = (const float*)d_in[24];

    const int* row  = eidx;
    const int* colp = eidx + ET_;

    float* W = (float*)d_ws;
    const size_t NTH = (size_t)NT_ * 64;
    float* b0    = W;                           // y -> y2 compact (+zero row NP2_)
    float* b1buf = W + 1*NTH;                   // hself -> hp -> v2buf
    float* b2buf = W + 2*NTH;                   // vbuf -> hp2
    float* b3buf = W + 3*NTH;                   // nsum -> hs2
    float* p = W + 4*NTH;
    int2*  rowcsr = (int2*)p;        p += 2*(size_t)ET_;
    int*   colcsr = (int*)p;         p += ET_;
    int*   ccsr2  = (int*)p;         p += ET_;
    int*   rowptr = (int*)p;         p += NT_ + 8;
    int*   colptr = (int*)p;         p += NT_ + 8;
    int*   histR8 = (int*)p;         p += NT_ * 8;
    int*   histC8 = (int*)p;         p += NT_ * 8;
    float* deg2   = p;               p += NP2_;
    float* tanhv  = p;               p += NP2_;
    int*   perm   = (int*)p;         p += NP2_;
    int*   nmap   = (int*)p;         p += NT_;
    int*   cls2   = (int*)p;         p += NP2_;
    float* BkT    = p;               p += 6 * 4096;
    float* PT     = p;               p += 6 * 256;
    float* statsP = p;               p += (size_t)G_ * 8 * 128;
    float* readP  = p;               p += (size_t)G_ * 6 * 128;
    float4* nsum  = (float4*)b3buf;             // stage-1 (live edge1f..gnprop)

    // ---- roots (gemm1 ∥ hist ∥ BkT ∥ PT in one launch) ----
    k_pregemm  <<<NT_/32 + 614, 256, 0, stream>>>(x, W1n, W1s, b1,
                                                  b0 /*y*/, b1buf /*hself*/,
                                                  row, colp, histR8, histC8,
                                                  BkTab, posW, posb, BkT, PT);
    k_scatscan <<<G_*4,    1024, 0, stream>>>(row, colp, eattr, histR8, histC8,
                                              rowcsr, colcsr, rowptr, colptr, nmap);
    k_edge1f   <<<NT_/4,   256, 0, stream>>>(rowptr, rowcsr, colptr, colcsr,
                                             coords, b0 /*y*/, b1buf /*hself*/,
                                             nsum, b2buf /*vbuf*/);
    k_gnstat   <<<G_*8,    256, 0, stream>>>(b2buf /*vbuf*/, statsP, N_, 8, 64);
    k_gnprop   <<<NT_/4,   256, 0, stream>>>(b2buf /*vbuf*/, statsP, gn1ms,
                                             gn1w, gn1b, nsum, acls, PT, BkT,
                                             b1buf /*hp (over hself)*/);
    k_topk     <<<G_,      512, 0, stream>>>(b1buf /*hp*/, poolp, acls, colcsr,
                                             row, colp, perm, tanhv, nmap,
                                             cls2, ccsr2, deg2);

    // ---- stage 2 ----
    k_s2prop   <<<NP2_/4,  256, 0, stream>>>(rowptr, rowcsr, perm, nmap, coords,
                                             b1buf /*hp*/, tanhv, cls2, PT, BkT,
                                             b2buf /*hp2*/,
                                             b0 + (size_t)NP2_ * 64 /*zero row*/);
    k_gemm2    <<<NP2_/32, 256, 0, stream>>>(b2buf /*hp2*/, W2n, W2s, b2,
                                             b0 /*y2 compact*/, b3buf /*hs2*/);
    k_gagg2v   <<<NP2_/4,  256, 0, stream>>>(colptr, ccsr2, perm, b0 /*y2*/,
                                             b3buf /*hs2*/, deg2,
                                             b1buf /*v2buf (over hp)*/);
    k_gnstat   <<<G_*6,    256, 0, stream>>>(b1buf /*v2buf*/, statsP, KP_, 6, 60);
    k_gnrd     <<<G_*6,    256, 0, stream>>>(b1buf /*v2buf*/, statsP, gn2ms,
                                             gn2w, gn2b, readP);
    k_rfin     <<<G_,      64,  0, stream>>>(readP, 6, l1W, l1b, l2W, l2b,
                                             (float*)d_out);
}